// Round 1
// 339.225 us; speedup vs baseline: 1.0062x; 1.0062x over previous
//
#include <hip/hip_runtime.h>
#include <hip/hip_bf16.h>

// Problem constants: B=4, S=2048, D=1024, H=16, dk=64
#define SEQ   2048
#define NB    4
#define NH    16
#define DK    64
#define DM    1024
#define MROWS (NB * SEQ)   // 8192

typedef __bf16 bf16_t;
typedef __bf16 bf16x8 __attribute__((ext_vector_type(8)));
typedef __bf16 bf16x4 __attribute__((ext_vector_type(4)));
typedef float  f32x4  __attribute__((ext_vector_type(4)));

#define MFMA16(a, b, c) __builtin_amdgcn_mfma_f32_16x16x32_bf16((a), (b), (c), 0, 0, 0)

// async global->LDS, 16B per lane; LDS dest wave-uniform, HW scatters +lane*16
__device__ __forceinline__ void gl2lds16(const bf16_t* g, bf16_t* l) {
    __builtin_amdgcn_global_load_lds(
        (const __attribute__((address_space(1))) unsigned int*)g,
        (__attribute__((address_space(3))) unsigned int*)l, 16, 0, 0);
}

// ---------------------------------------------------------------------------
// fp32 -> bf16 conversion (x)
// ---------------------------------------------------------------------------
__global__ __launch_bounds__(256) void cvt_kernel(
    const float* __restrict__ in, bf16_t* __restrict__ out, int n)
{
    int i = (blockIdx.x * 256 + threadIdx.x) * 4;
    if (i + 3 < n) {
        const float4 v = *(const float4*)(in + i);
        bf16x4 o;
        o[0] = (bf16_t)v.x; o[1] = (bf16_t)v.y;
        o[2] = (bf16_t)v.z; o[3] = (bf16_t)v.w;
        *(bf16x4*)(out + i) = o;
    }
}

// ---------------------------------------------------------------------------
// Weight transpose + cast: Wt[n][k] = (bf16)W[k][n].  32x32 tiles via LDS.
// ---------------------------------------------------------------------------
__global__ __launch_bounds__(256) void wtr_kernel(
    const float* __restrict__ W, bf16_t* __restrict__ Wt)
{
    __shared__ float T[32][33];
    const int tk0 = (blockIdx.x >> 5) << 5;
    const int tn0 = (blockIdx.x & 31) << 5;
    const int r = threadIdx.x >> 5, c = threadIdx.x & 31;
#pragma unroll
    for (int i = 0; i < 4; ++i)
        T[r + i * 8][c] = W[(size_t)(tk0 + r + i * 8) * DM + tn0 + c];
    __syncthreads();
#pragma unroll
    for (int i = 0; i < 4; ++i)
        Wt[(size_t)(tn0 + r + i * 8) * DM + tk0 + c] = (bf16_t)T[c][r + i * 8];
}

// ---------------------------------------------------------------------------
// RoPE table: tab[s*32+i] = (cos, sin) of s * 10000^(-i/32)
// ---------------------------------------------------------------------------
__global__ void rope_table_kernel(float2* __restrict__ tab) {
    int idx = blockIdx.x * 256 + threadIdx.x;
    if (idx >= SEQ * 32) return;
    int s = idx >> 5, i = idx & 31;
    float freq = powf(10000.0f, -(float)i / 32.0f);
    float a = (float)s * freq;
    tab[idx] = make_float2(cosf(a), sinf(a));
}

// ---------------------------------------------------------------------------
// 128x128xK(BK=32) MFMA K-loop, TRIPLE-buffered, prefetch distance 2.
// Raw s_barrier + counted s_waitcnt vmcnt(4): the 4 loads of the NEXT chunk
// stay in flight across the barrier (never drain to 0 in steady state).
// Safety: a wave's MFMAs consume its ds_reads before it reaches the barrier
// (lgkm data dep), so once all waves pass barrier k, buffer (k+2)%3 (holding
// chunk k-1's data) is no longer being read and may be overwritten.
// LDS layout per buffer: 8 groups of 512 elems; group g holds rows g*16..+15,
// lane i <-> (row i&15, k (i>>4)*8), so frags are lane-contiguous b128 reads.
// TR is compile-time: swaps MFMA operands to produce C^T (for V epilogue).
// ---------------------------------------------------------------------------
template<bool TR>
__device__ __forceinline__ void kloop128(
    const bf16_t* __restrict__ Xp, const bf16_t* __restrict__ Wp,
    bf16_t* As, bf16_t* Bs, int tid, f32x4 (&acc)[4][4], int kiters)
{
    const int lane = tid & 63;
    const int wave = tid >> 6;
    const int wm = wave & 1, wn = wave >> 1;
    const int l = lane & 15, quad = lane >> 4;
    const int rl = lane & 15;
    const int kf = (lane >> 4) << 3;
    const int gA = wave * 2;

    const bf16_t* xa0 = Xp + (size_t)(gA * 16 + rl) * DM + kf;
    const bf16_t* xa1 = Xp + (size_t)((gA + 1) * 16 + rl) * DM + kf;
    const bf16_t* wb0 = Wp + (size_t)(gA * 16 + rl) * DM + kf;
    const bf16_t* wb1 = Wp + (size_t)((gA + 1) * 16 + rl) * DM + kf;

#define STAGE(J, BUF) do {                                          \
        const int _ko = (J) * 32;                                   \
        gl2lds16(xa0 + _ko, As + (BUF) * 4096 + gA * 512);          \
        gl2lds16(xa1 + _ko, As + (BUF) * 4096 + (gA + 1) * 512);    \
        gl2lds16(wb0 + _ko, Bs + (BUF) * 4096 + gA * 512);          \
        gl2lds16(wb1 + _ko, Bs + (BUF) * 4096 + (gA + 1) * 512);    \
    } while (0)

    // prologue: chunks 0 and 1 in flight before first wait
    STAGE(0, 0);
    STAGE(1, 1);

    int cur = 0;   // buffer holding chunk k
    int pre = 2;   // buffer to stage chunk k+2 into
    for (int k = 0; k < kiters; ++k) {
        // wait: oldest 4 loads (chunk k) landed; chunk k+1's 4 stay in flight
        if (k + 1 < kiters) {
            asm volatile("s_waitcnt vmcnt(4)\n\ts_barrier" ::: "memory");
        } else {
            asm volatile("s_waitcnt vmcnt(0)\n\ts_barrier" ::: "memory");
        }
        if (k + 2 < kiters) STAGE(k + 2, pre);

        const bf16_t* ab = As + cur * 4096;
        const bf16_t* bb = Bs + cur * 4096;
        bf16x8 af[4], bw[4];
#pragma unroll
        for (int a = 0; a < 4; ++a) {
            af[a] = *(const bf16x8*)(ab + (wm * 4 + a) * 512 + (quad * 16 + l) * 8);
            bw[a] = *(const bf16x8*)(bb + (wn * 4 + a) * 512 + (quad * 16 + l) * 8);
        }
#pragma unroll
        for (int a = 0; a < 4; ++a)
#pragma unroll
            for (int b = 0; b < 4; ++b)
                acc[a][b] = TR ? MFMA16(bw[b], af[a], acc[a][b])
                               : MFMA16(af[a], bw[b], acc[a][b]);

        cur = (cur == 2) ? 0 : cur + 1;
        pre = (pre == 2) ? 0 : pre + 1;
    }
#undef STAGE
}

// ---------------------------------------------------------------------------
// Merged QKV GEMM: C = X(8192x1024) @ Wqkv^T, Wqkv stored [3072][1024].
// Epilogue by n0: n<1024 Q (RoPE*1/8), n<2048 K (RoPE), else V (C^T direct).
// ---------------------------------------------------------------------------
__global__ __launch_bounds__(256) void gemm_qkv_kernel(
    const bf16_t* __restrict__ X, const bf16_t* __restrict__ Wt,
    bf16_t* __restrict__ Qt, bf16_t* __restrict__ Kt, bf16_t* __restrict__ Vtr,
    const float2* __restrict__ rope)
{
    __shared__ __align__(16) bf16_t As[3 * 128 * 32];
    __shared__ __align__(16) bf16_t Bs[3 * 128 * 32];

    const int tid  = threadIdx.x;
    const int lane = tid & 63;
    const int wave = tid >> 6;
    const int wm   = wave & 1, wn = wave >> 1;
    const int l    = lane & 15;
    const int quad = lane >> 4;

    const int m0 = (blockIdx.x / 24) << 7;
    const int n0 = (blockIdx.x % 24) << 7;
    const bool tr = (n0 >= 2 * DM);   // V range

    f32x4 acc[4][4] = {};
    if (tr) kloop128<true >(X + (size_t)m0 * DM, Wt + (size_t)n0 * DM, As, Bs, tid, acc, DM / 32);
    else    kloop128<false>(X + (size_t)m0 * DM, Wt + (size_t)n0 * DM, As, Bs, tid, acc, DM / 32);

#pragma unroll
    for (int a = 0; a < 4; ++a)
#pragma unroll
        for (int b = 0; b < 4; ++b)
#pragma unroll
            for (int r = 0; r < 4; ++r) {
                float v = acc[a][b][r];
                if (tr) {
                    const int n = n0 + wn * 64 + b * 16 + quad * 4 + r;
                    const int m = m0 + wm * 64 + a * 16 + l;
                    const int bi = m >> 11, s = m & (SEQ - 1);
                    const int col = n & (DM - 1);
                    const int h = col >> 6, d = col & (DK - 1);
                    Vtr[(((size_t)(bi * NH + h)) * DK + d) * SEQ + s] = (bf16_t)v;
                } else {
                    const int m  = m0 + wm * 64 + a * 16 + quad * 4 + r;
                    const int nn = n0 + wn * 64 + b * 16 + l;
                    const int bi = m >> 11, s = m & (SEQ - 1);
                    const int col = nn & (DM - 1);
                    const int h = col >> 6, d = col & (DK - 1);
                    float pv = __shfl_xor(v, 1);
                    float2 cs = rope[s * 32 + (d >> 1)];
                    float res = (d & 1) ? (v * cs.x + pv * cs.y)
                                        : (v * cs.x - pv * cs.y);
                    bf16_t* dst = (nn < DM) ? Qt : Kt;
                    if (nn < DM) res *= 0.125f;   // fold 1/sqrt(dk) into Q
                    dst[(((size_t)(bi * NH + h)) * SEQ + s) * DK + d] = (bf16_t)res;
                }
            }
}

// ---------------------------------------------------------------------------
// Output projection GEMM: d_out(fp32) = Ot(8192x1024,bf16) @ Wot^T.
// ---------------------------------------------------------------------------
__global__ __launch_bounds__(256) void gemm_out_kernel(
    const bf16_t* __restrict__ X, const bf16_t* __restrict__ Wt,
    float* __restrict__ out)
{
    __shared__ __align__(16) bf16_t As[3 * 128 * 32];
    __shared__ __align__(16) bf16_t Bs[3 * 128 * 32];

    const int tid  = threadIdx.x;
    const int lane = tid & 63;
    const int wave = tid >> 6;
    const int wm   = wave & 1, wn = wave >> 1;
    const int l    = lane & 15;
    const int quad = lane >> 4;

    const int m0 = (blockIdx.x >> 3) << 7;
    const int n0 = (blockIdx.x & 7) << 7;

    f32x4 acc[4][4] = {};
    kloop128<false>(X + (size_t)m0 * DM, Wt + (size_t)n0 * DM, As, Bs, tid, acc, DM / 32);

#pragma unroll
    for (int a = 0; a < 4; ++a)
#pragma unroll
        for (int b = 0; b < 4; ++b)
#pragma unroll
            for (int r = 0; r < 4; ++r) {
                const int m  = m0 + wm * 64 + a * 16 + quad * 4 + r;
                const int nn = n0 + wn * 64 + b * 16 + l;
                out[(size_t)m * DM + nn] = acc[a][b][r];
            }
}

// ---------------------------------------------------------------------------
// Causal flash attention (unchanged).
// ---------------------------------------------------------------------------
#define KLD 72   // LDS row stride (elems): 144 B

__global__ __launch_bounds__(256) void attn_kernel(
    const bf16_t* __restrict__ Q, const bf16_t* __restrict__ K,
    const bf16_t* __restrict__ Vt, bf16_t* __restrict__ O)
{
    __shared__ __align__(16) bf16_t Kl[64 * KLD];
    __shared__ __align__(16) bf16_t Vl[64 * KLD];
    __shared__ __align__(16) bf16_t Pl[4][32 * KLD];

    const int bh   = blockIdx.y;
    const int tid  = threadIdx.x;
    const int wave = tid >> 6;
    const int lane = tid & 63;
    const int l    = lane & 15;
    const int quad = lane >> 4;
    const int srow = tid >> 3;
    const int sch  = (tid & 7) << 3;

    bf16_t* Pw = Pl[wave];
    const bf16_t* Qb = Q  + (size_t)bh * SEQ * DK;
    const bf16_t* Kb = K  + (size_t)bh * SEQ * DK;
    const bf16_t* Vb = Vt + (size_t)bh * DK * SEQ;
    const int b = bh >> 4, h = bh & 15;

    for (int ph = 0; ph < 2; ++ph) {
        const int qblk = ph ? (15 - (int)blockIdx.x) : (int)blockIdx.x;
        const int q0w  = qblk * 128 + wave * 32;
        const int nch  = 2 * (qblk + 1);

        bf16x8 qb[2][2];
#pragma unroll
        for (int u = 0; u < 2; ++u) {
            qb[u][0] = *(const bf16x8*)(Qb + (size_t)(q0w + u * 16 + l) * DK + quad * 8);
            qb[u][1] = *(const bf16x8*)(Qb + (size_t)(q0w + u * 16 + l) * DK + 32 + quad * 8);
        }

        float m_run[2] = {-3e38f, -3e38f};
        float l_run[2] = {0.f, 0.f};
        f32x4 o[4][2] = {};

        bf16x8 pk0 = *(const bf16x8*)(Kb + (size_t)srow * DK + sch);
        bf16x8 pk1 = *(const bf16x8*)(Kb + (size_t)(32 + srow) * DK + sch);
        bf16x8 pv0 = *(const bf16x8*)(Vb + (size_t)srow * SEQ + sch);
        bf16x8 pv1 = *(const bf16x8*)(Vb + (size_t)(32 + srow) * SEQ + sch);

        for (int i = 0; i < nch; ++i) {
            const int c = i * 64;
            __syncthreads();
            *(bf16x8*)(Kl + srow * KLD + sch)        = pk0;
            *(bf16x8*)(Kl + (32 + srow) * KLD + sch) = pk1;
            *(bf16x8*)(Vl + srow * KLD + sch)        = pv0;
            *(bf16x8*)(Vl + (32 + srow) * KLD + sch) = pv1;
            __syncthreads();
            if (i + 1 < nch) {
                const int cn = c + 64;
                pk0 = *(const bf16x8*)(Kb + (size_t)(cn + srow) * DK + sch);
                pk1 = *(const bf16x8*)(Kb + (size_t)(cn + 32 + srow) * DK + sch);
                pv0 = *(const bf16x8*)(Vb + (size_t)srow * SEQ + cn + sch);
                pv1 = *(const bf16x8*)(Vb + (size_t)(32 + srow) * SEQ + cn + sch);
            }
            if (c > q0w + 31) continue;

            f32x4 st[4][2] = {};
#pragma unroll
            for (int t = 0; t < 4; ++t) {
                const bf16x8 k0 = *(const bf16x8*)(Kl + (t * 16 + l) * KLD + quad * 8);
                const bf16x8 k1 = *(const bf16x8*)(Kl + (t * 16 + l) * KLD + 32 + quad * 8);
                st[t][0] = MFMA16(k0, qb[0][0], st[t][0]);
                st[t][0] = MFMA16(k1, qb[0][1], st[t][0]);
                st[t][1] = MFMA16(k0, qb[1][0], st[t][1]);
                st[t][1] = MFMA16(k1, qb[1][1], st[t][1]);
            }
            if (c + 63 > q0w) {
#pragma unroll
                for (int u = 0; u < 2; ++u) {
                    const int thr = q0w + u * 16 + l - c - quad * 4;
#pragma unroll
                    for (int t = 0; t < 4; ++t)
#pragma unroll
                        for (int r = 0; r < 4; ++r)
                            if (t * 16 + r > thr) st[t][u][r] = -3e38f;
                }
            }
#pragma unroll
            for (int u = 0; u < 2; ++u) {
                float cmax = -3e38f;
#pragma unroll
                for (int t = 0; t < 4; ++t)
#pragma unroll
                    for (int r = 0; r < 4; ++r)
                        cmax = fmaxf(cmax, st[t][u][r]);
                cmax = fmaxf(cmax, __shfl_xor(cmax, 16));
                cmax = fmaxf(cmax, __shfl_xor(cmax, 32));
                const float mnew  = fmaxf(m_run[u], cmax);
                const float alpha = __expf(m_run[u] - mnew);
                m_run[u] = mnew;
                float csum = 0.f;
#pragma unroll
                for (int t = 0; t < 4; ++t)
#pragma unroll
                    for (int r = 0; r < 4; ++r) {
                        st[t][u][r] = __expf(st[t][u][r] - mnew);
                        csum += st[t][u][r];
                    }
                csum += __shfl_xor(csum, 16);
                csum += __shfl_xor(csum, 32);
                l_run[u] = l_run[u] * alpha + csum;
#pragma unroll
                for (int n = 0; n < 4; ++n)
#pragma unroll
                    for (int r = 0; r < 4; ++r)
                        o[n][u][r] *= alpha;
#pragma unroll
                for (int t = 0; t < 4; ++t) {
                    bf16x4 pk;
                    pk[0] = (bf16_t)st[t][u][0]; pk[1] = (bf16_t)st[t][u][1];
                    pk[2] = (bf16_t)st[t][u][2]; pk[3] = (bf16_t)st[t][u][3];
                    *(bf16x4*)(Pw + (u * 16 + l) * KLD + t * 16 + quad * 4) = pk;
                }
            }
            const bf16x8 pb00 = *(const bf16x8*)(Pw + l * KLD + quad * 8);
            const bf16x8 pb01 = *(const bf16x8*)(Pw + l * KLD + 32 + quad * 8);
            const bf16x8 pb10 = *(const bf16x8*)(Pw + (16 + l) * KLD + quad * 8);
            const bf16x8 pb11 = *(const bf16x8*)(Pw + (16 + l) * KLD + 32 + quad * 8);
#pragma unroll
            for (int n = 0; n < 4; ++n) {
                const bf16x8 v0 = *(const bf16x8*)(Vl + (n * 16 + l) * KLD + quad * 8);
                const bf16x8 v1 = *(const bf16x8*)(Vl + (n * 16 + l) * KLD + 32 + quad * 8);
                o[n][0] = MFMA16(v0, pb00, o[n][0]);
                o[n][0] = MFMA16(v1, pb01, o[n][0]);
                o[n][1] = MFMA16(v0, pb10, o[n][1]);
                o[n][1] = MFMA16(v1, pb11, o[n][1]);
            }
        }

#pragma unroll
        for (int u = 0; u < 2; ++u) {
            const float inv = 1.0f / l_run[u];
#pragma unroll
            for (int n = 0; n < 4; ++n) {
                bf16x4 ov;
                ov[0] = (bf16_t)(o[n][u][0] * inv); ov[1] = (bf16_t)(o[n][u][1] * inv);
                ov[2] = (bf16_t)(o[n][u][2] * inv); ov[3] = (bf16_t)(o[n][u][3] * inv);
                *(bf16x4*)(Pw + (u * 16 + l) * KLD + n * 16 + quad * 4) = ov;
            }
        }
        const int row  = lane >> 1;
        const int half = (lane & 1) * 32;
        const bf16x8 w0 = *(const bf16x8*)(Pw + row * KLD + half);
        const bf16x8 w1 = *(const bf16x8*)(Pw + row * KLD + half + 8);
        const bf16x8 w2 = *(const bf16x8*)(Pw + row * KLD + half + 16);
        const bf16x8 w3 = *(const bf16x8*)(Pw + row * KLD + half + 24);
        bf16_t* op = O + ((size_t)(b * SEQ + qblk * 128 + wave * 32 + row)) * DM
                       + h * DK + half;
        *(bf16x8*)(op)      = w0;
        *(bf16x8*)(op + 8)  = w1;
        *(bf16x8*)(op + 16) = w2;
        *(bf16x8*)(op + 24) = w3;
    }
}

// ---------------------------------------------------------------------------
extern "C" void kernel_launch(void* const* d_in, const int* in_sizes, int n_in,
                              void* d_out, int out_size, void* d_ws, size_t ws_size,
                              hipStream_t stream)
{
    const float* x  = (const float*)d_in[0];
    const float* Wq = (const float*)d_in[1];
    const float* Wk = (const float*)d_in[2];
    const float* Wv = (const float*)d_in[3];
    const float* Wo = (const float*)d_in[4];

    char* ws = (char*)d_ws;
    float2* rope = (float2*)ws;                        // 512 KiB
    const size_t TEN = (size_t)MROWS * DM;
    const size_t WEL = (size_t)DM * DM;
    bf16_t* xb    = (bf16_t*)(ws + (1 << 19));
    bf16_t* Wqkvt = xb + TEN;                          // [3072][1024] concat
    bf16_t* Wot   = Wqkvt + 3 * WEL;
    bf16_t* Qt    = Wot + WEL;
    bf16_t* Kt    = Qt + TEN;
    bf16_t* Vt    = Kt + TEN;
    bf16_t* Ot    = Vt + TEN;

    rope_table_kernel<<<(SEQ * 32 + 255) / 256, 256, 0, stream>>>(rope);

    cvt_kernel<<<(int)(TEN / 4 / 256), 256, 0, stream>>>(x, xb, (int)TEN);
    wtr_kernel<<<1024, 256, 0, stream>>>(Wq, Wqkvt);
    wtr_kernel<<<1024, 256, 0, stream>>>(Wk, Wqkvt + WEL);
    wtr_kernel<<<1024, 256, 0, stream>>>(Wv, Wqkvt + 2 * WEL);
    wtr_kernel<<<1024, 256, 0, stream>>>(Wo, Wot);

    // merged QKV: 64 m-tiles x 24 n-tiles
    gemm_qkv_kernel<<<64 * 24, 256, 0, stream>>>(xb, Wqkvt, Qt, Kt, Vt, rope);

    attn_kernel<<<dim3(8, NB * NH), 256, 0, stream>>>(Qt, Kt, Vt, Ot);

    gemm_out_kernel<<<64 * 8, 256, 0, stream>>>(Ot, Wot, (float*)d_out);
}

// Round 2
// 338.166 us; speedup vs baseline: 1.0094x; 1.0031x over previous
//
#include <hip/hip_runtime.h>
#include <hip/hip_bf16.h>

// Problem constants: B=4, S=2048, D=1024, H=16, dk=64
#define SEQ   2048
#define NB    4
#define NH    16
#define DK    64
#define DM    1024
#define MROWS (NB * SEQ)   // 8192

typedef __bf16 bf16_t;
typedef __bf16 bf16x8 __attribute__((ext_vector_type(8)));
typedef __bf16 bf16x4 __attribute__((ext_vector_type(4)));
typedef float  f32x4  __attribute__((ext_vector_type(4)));

#define MFMA16(a, b, c) __builtin_amdgcn_mfma_f32_16x16x32_bf16((a), (b), (c), 0, 0, 0)

// async global->LDS, 16B per lane; LDS dest wave-uniform, HW scatters +lane*16
__device__ __forceinline__ void gl2lds16(const bf16_t* g, bf16_t* l) {
    __builtin_amdgcn_global_load_lds(
        (const __attribute__((address_space(1))) unsigned int*)g,
        (__attribute__((address_space(3))) unsigned int*)l, 16, 0, 0);
}

// ---------------------------------------------------------------------------
// fp32 -> bf16 conversion (x)
// ---------------------------------------------------------------------------
__global__ __launch_bounds__(256) void cvt_kernel(
    const float* __restrict__ in, bf16_t* __restrict__ out, int n)
{
    int i = (blockIdx.x * 256 + threadIdx.x) * 4;
    if (i + 3 < n) {
        const float4 v = *(const float4*)(in + i);
        bf16x4 o;
        o[0] = (bf16_t)v.x; o[1] = (bf16_t)v.y;
        o[2] = (bf16_t)v.z; o[3] = (bf16_t)v.w;
        *(bf16x4*)(out + i) = o;
    }
}

// ---------------------------------------------------------------------------
// Weight transpose + cast: Wt[n][k] = (bf16)W[k][n].  32x32 tiles via LDS.
// ---------------------------------------------------------------------------
__global__ __launch_bounds__(256) void wtr_kernel(
    const float* __restrict__ W, bf16_t* __restrict__ Wt)
{
    __shared__ float T[32][33];
    const int tk0 = (blockIdx.x >> 5) << 5;
    const int tn0 = (blockIdx.x & 31) << 5;
    const int r = threadIdx.x >> 5, c = threadIdx.x & 31;
#pragma unroll
    for (int i = 0; i < 4; ++i)
        T[r + i * 8][c] = W[(size_t)(tk0 + r + i * 8) * DM + tn0 + c];
    __syncthreads();
#pragma unroll
    for (int i = 0; i < 4; ++i)
        Wt[(size_t)(tn0 + r + i * 8) * DM + tk0 + c] = (bf16_t)T[c][r + i * 8];
}

// ---------------------------------------------------------------------------
// RoPE table: tab[s*32+i] = (cos, sin) of s * 10000^(-i/32)
// ---------------------------------------------------------------------------
__global__ void rope_table_kernel(float2* __restrict__ tab) {
    int idx = blockIdx.x * 256 + threadIdx.x;
    if (idx >= SEQ * 32) return;
    int s = idx >> 5, i = idx & 31;
    float freq = powf(10000.0f, -(float)i / 32.0f);
    float a = (float)s * freq;
    tab[idx] = make_float2(cosf(a), sinf(a));
}

// ---------------------------------------------------------------------------
// 128x128xK(BK=32) MFMA K-loop, TRIPLE-buffered, prefetch distance 2.
// Raw s_barrier + counted s_waitcnt vmcnt(4): the 4 loads of the NEXT chunk
// stay in flight across the barrier (never drain to 0 in steady state).
// LDS layout per buffer: 8 groups of 512 elems; group g holds rows g*16..+15,
// lane i <-> (row i&15, k (i>>4)*8), so frags are lane-contiguous b128 reads.
// TR is compile-time: swaps MFMA operands to produce C^T (for V epilogue).
// ---------------------------------------------------------------------------
template<bool TR>
__device__ __forceinline__ void kloop128(
    const bf16_t* __restrict__ Xp, const bf16_t* __restrict__ Wp,
    bf16_t* As, bf16_t* Bs, int tid, f32x4 (&acc)[4][4], int kiters)
{
    const int lane = tid & 63;
    const int wave = tid >> 6;
    const int wm = wave & 1, wn = wave >> 1;
    const int l = lane & 15, quad = lane >> 4;
    const int rl = lane & 15;
    const int kf = (lane >> 4) << 3;
    const int gA = wave * 2;

    const bf16_t* xa0 = Xp + (size_t)(gA * 16 + rl) * DM + kf;
    const bf16_t* xa1 = Xp + (size_t)((gA + 1) * 16 + rl) * DM + kf;
    const bf16_t* wb0 = Wp + (size_t)(gA * 16 + rl) * DM + kf;
    const bf16_t* wb1 = Wp + (size_t)((gA + 1) * 16 + rl) * DM + kf;

#define STAGE(J, BUF) do {                                          \
        const int _ko = (J) * 32;                                   \
        gl2lds16(xa0 + _ko, As + (BUF) * 4096 + gA * 512);          \
        gl2lds16(xa1 + _ko, As + (BUF) * 4096 + (gA + 1) * 512);    \
        gl2lds16(wb0 + _ko, Bs + (BUF) * 4096 + gA * 512);          \
        gl2lds16(wb1 + _ko, Bs + (BUF) * 4096 + (gA + 1) * 512);    \
    } while (0)

    // prologue: chunks 0 and 1 in flight before first wait
    STAGE(0, 0);
    STAGE(1, 1);

    int cur = 0;   // buffer holding chunk k
    int pre = 2;   // buffer to stage chunk k+2 into
    for (int k = 0; k < kiters; ++k) {
        // wait: oldest 4 loads (chunk k) landed; chunk k+1's 4 stay in flight
        if (k + 1 < kiters) {
            asm volatile("s_waitcnt vmcnt(4)\n\ts_barrier" ::: "memory");
        } else {
            asm volatile("s_waitcnt vmcnt(0)\n\ts_barrier" ::: "memory");
        }
        if (k + 2 < kiters) STAGE(k + 2, pre);

        const bf16_t* ab = As + cur * 4096;
        const bf16_t* bb = Bs + cur * 4096;
        bf16x8 af[4], bw[4];
#pragma unroll
        for (int a = 0; a < 4; ++a) {
            af[a] = *(const bf16x8*)(ab + (wm * 4 + a) * 512 + (quad * 16 + l) * 8);
            bw[a] = *(const bf16x8*)(bb + (wn * 4 + a) * 512 + (quad * 16 + l) * 8);
        }
#pragma unroll
        for (int a = 0; a < 4; ++a)
#pragma unroll
            for (int b = 0; b < 4; ++b)
                acc[a][b] = TR ? MFMA16(bw[b], af[a], acc[a][b])
                               : MFMA16(af[a], bw[b], acc[a][b]);

        cur = (cur == 2) ? 0 : cur + 1;
        pre = (pre == 2) ? 0 : pre + 1;
    }
#undef STAGE
}

// ---------------------------------------------------------------------------
// Merged QKV GEMM: C = X(8192x1024) @ Wqkv^T, Wqkv stored [3072][1024].
// Epilogue by n0: n<1024 Q (RoPE*1/8), n<2048 K (RoPE), else V (C^T direct).
// Block swizzle: XCD-region mapping.  nwg=1536=8 XCD x 192.  Each XCD owns a
// 16m x 12n tile region (region grid 4x2); within a region blocks go n-fastest
// so ~96 co-resident blocks/XCD touch ~8 A-panels (2MB) + 12 B-panels (3MB),
// fitting the 4MB per-XCD L2 instead of the unswizzled ~14MB thrash.
// ---------------------------------------------------------------------------
__global__ __launch_bounds__(256) void gemm_qkv_kernel(
    const bf16_t* __restrict__ X, const bf16_t* __restrict__ Wt,
    bf16_t* __restrict__ Qt, bf16_t* __restrict__ Kt, bf16_t* __restrict__ Vtr,
    const float2* __restrict__ rope)
{
    __shared__ __align__(16) bf16_t As[3 * 128 * 32];
    __shared__ __align__(16) bf16_t Bs[3 * 128 * 32];

    const int tid  = threadIdx.x;
    const int lane = tid & 63;
    const int wave = tid >> 6;
    const int wm   = wave & 1, wn = wave >> 1;
    const int l    = lane & 15;
    const int quad = lane >> 4;

    const int orig = blockIdx.x;        // 0..1535, HW round-robins orig%8 -> XCD
    const int xcd  = orig & 7;
    const int idx  = orig >> 3;         // 0..191, ascending within an XCD
    const int mt   = (xcd >> 1) * 16 + idx / 12;   // 0..63
    const int nt   = (xcd & 1) * 12 + idx % 12;    // 0..23
    const int m0 = mt << 7;
    const int n0 = nt << 7;
    const bool tr = (n0 >= 2 * DM);   // V range

    f32x4 acc[4][4] = {};
    if (tr) kloop128<true >(X + (size_t)m0 * DM, Wt + (size_t)n0 * DM, As, Bs, tid, acc, DM / 32);
    else    kloop128<false>(X + (size_t)m0 * DM, Wt + (size_t)n0 * DM, As, Bs, tid, acc, DM / 32);

#pragma unroll
    for (int a = 0; a < 4; ++a)
#pragma unroll
        for (int b = 0; b < 4; ++b)
#pragma unroll
            for (int r = 0; r < 4; ++r) {
                float v = acc[a][b][r];
                if (tr) {
                    const int n = n0 + wn * 64 + b * 16 + quad * 4 + r;
                    const int m = m0 + wm * 64 + a * 16 + l;
                    const int bi = m >> 11, s = m & (SEQ - 1);
                    const int col = n & (DM - 1);
                    const int h = col >> 6, d = col & (DK - 1);
                    Vtr[(((size_t)(bi * NH + h)) * DK + d) * SEQ + s] = (bf16_t)v;
                } else {
                    const int m  = m0 + wm * 64 + a * 16 + quad * 4 + r;
                    const int nn = n0 + wn * 64 + b * 16 + l;
                    const int bi = m >> 11, s = m & (SEQ - 1);
                    const int col = nn & (DM - 1);
                    const int h = col >> 6, d = col & (DK - 1);
                    float pv = __shfl_xor(v, 1);
                    float2 cs = rope[s * 32 + (d >> 1)];
                    float res = (d & 1) ? (v * cs.x + pv * cs.y)
                                        : (v * cs.x - pv * cs.y);
                    bf16_t* dst = (nn < DM) ? Qt : Kt;
                    if (nn < DM) res *= 0.125f;   // fold 1/sqrt(dk) into Q
                    dst[(((size_t)(bi * NH + h)) * SEQ + s) * DK + d] = (bf16_t)res;
                }
            }
}

// ---------------------------------------------------------------------------
// Output projection GEMM: d_out(fp32) = Ot(8192x1024,bf16) @ Wot^T.
// Swizzle: nwg=512=8 XCD x 64; XCD i owns an 8m x 8n region = 2MB A + 2MB B
// = 4MB, exactly one L2.  All 512 blocks co-resident.
// ---------------------------------------------------------------------------
__global__ __launch_bounds__(256) void gemm_out_kernel(
    const bf16_t* __restrict__ X, const bf16_t* __restrict__ Wt,
    float* __restrict__ out)
{
    __shared__ __align__(16) bf16_t As[3 * 128 * 32];
    __shared__ __align__(16) bf16_t Bs[3 * 128 * 32];

    const int tid  = threadIdx.x;
    const int lane = tid & 63;
    const int wave = tid >> 6;
    const int wm   = wave & 1, wn = wave >> 1;
    const int l    = lane & 15;
    const int quad = lane >> 4;

    const int orig = blockIdx.x;        // 0..511
    const int xcd  = orig & 7;
    const int idx  = orig >> 3;         // 0..63
    const int m0 = ((xcd << 3) + (idx >> 3)) << 7;
    const int n0 = (idx & 7) << 7;

    f32x4 acc[4][4] = {};
    kloop128<false>(X + (size_t)m0 * DM, Wt + (size_t)n0 * DM, As, Bs, tid, acc, DM / 32);

#pragma unroll
    for (int a = 0; a < 4; ++a)
#pragma unroll
        for (int b = 0; b < 4; ++b)
#pragma unroll
            for (int r = 0; r < 4; ++r) {
                const int m  = m0 + wm * 64 + a * 16 + quad * 4 + r;
                const int nn = n0 + wn * 64 + b * 16 + l;
                out[(size_t)m * DM + nn] = acc[a][b][r];
            }
}

// ---------------------------------------------------------------------------
// Causal flash attention.  Grid swizzled to (bh, qchunk) so linear bid % 8 =
// bh % 8: each XCD serves 8 heads -> 8 x 512KB K/V = 4MB, fits its L2, and
// the 8 q-chunk blocks of one head stream the same K/V (L2 hits) instead of
// every XCD pulling all 32MB.
// ---------------------------------------------------------------------------
#define KLD 72   // LDS row stride (elems): 144 B

__global__ __launch_bounds__(256) void attn_kernel(
    const bf16_t* __restrict__ Q, const bf16_t* __restrict__ K,
    const bf16_t* __restrict__ Vt, bf16_t* __restrict__ O)
{
    __shared__ __align__(16) bf16_t Kl[64 * KLD];
    __shared__ __align__(16) bf16_t Vl[64 * KLD];
    __shared__ __align__(16) bf16_t Pl[4][32 * KLD];

    const int bh   = blockIdx.x;          // swizzle: bh is fast dim
    const int qx   = blockIdx.y;          // q-chunk index 0..7
    const int tid  = threadIdx.x;
    const int wave = tid >> 6;
    const int lane = tid & 63;
    const int l    = lane & 15;
    const int quad = lane >> 4;
    const int srow = tid >> 3;
    const int sch  = (tid & 7) << 3;

    bf16_t* Pw = Pl[wave];
    const bf16_t* Qb = Q  + (size_t)bh * SEQ * DK;
    const bf16_t* Kb = K  + (size_t)bh * SEQ * DK;
    const bf16_t* Vb = Vt + (size_t)bh * DK * SEQ;
    const int b = bh >> 4, h = bh & 15;

    for (int ph = 0; ph < 2; ++ph) {
        const int qblk = ph ? (15 - qx) : qx;
        const int q0w  = qblk * 128 + wave * 32;
        const int nch  = 2 * (qblk + 1);

        bf16x8 qb[2][2];
#pragma unroll
        for (int u = 0; u < 2; ++u) {
            qb[u][0] = *(const bf16x8*)(Qb + (size_t)(q0w + u * 16 + l) * DK + quad * 8);
            qb[u][1] = *(const bf16x8*)(Qb + (size_t)(q0w + u * 16 + l) * DK + 32 + quad * 8);
        }

        float m_run[2] = {-3e38f, -3e38f};
        float l_run[2] = {0.f, 0.f};
        f32x4 o[4][2] = {};

        bf16x8 pk0 = *(const bf16x8*)(Kb + (size_t)srow * DK + sch);
        bf16x8 pk1 = *(const bf16x8*)(Kb + (size_t)(32 + srow) * DK + sch);
        bf16x8 pv0 = *(const bf16x8*)(Vb + (size_t)srow * SEQ + sch);
        bf16x8 pv1 = *(const bf16x8*)(Vb + (size_t)(32 + srow) * SEQ + sch);

        for (int i = 0; i < nch; ++i) {
            const int c = i * 64;
            __syncthreads();
            *(bf16x8*)(Kl + srow * KLD + sch)        = pk0;
            *(bf16x8*)(Kl + (32 + srow) * KLD + sch) = pk1;
            *(bf16x8*)(Vl + srow * KLD + sch)        = pv0;
            *(bf16x8*)(Vl + (32 + srow) * KLD + sch) = pv1;
            __syncthreads();
            if (i + 1 < nch) {
                const int cn = c + 64;
                pk0 = *(const bf16x8*)(Kb + (size_t)(cn + srow) * DK + sch);
                pk1 = *(const bf16x8*)(Kb + (size_t)(cn + 32 + srow) * DK + sch);
                pv0 = *(const bf16x8*)(Vb + (size_t)srow * SEQ + cn + sch);
                pv1 = *(const bf16x8*)(Vb + (size_t)(32 + srow) * SEQ + cn + sch);
            }
            if (c > q0w + 31) continue;

            f32x4 st[4][2] = {};
#pragma unroll
            for (int t = 0; t < 4; ++t) {
                const bf16x8 k0 = *(const bf16x8*)(Kl + (t * 16 + l) * KLD + quad * 8);
                const bf16x8 k1 = *(const bf16x8*)(Kl + (t * 16 + l) * KLD + 32 + quad * 8);
                st[t][0] = MFMA16(k0, qb[0][0], st[t][0]);
                st[t][0] = MFMA16(k1, qb[0][1], st[t][0]);
                st[t][1] = MFMA16(k0, qb[1][0], st[t][1]);
                st[t][1] = MFMA16(k1, qb[1][1], st[t][1]);
            }
            if (c + 63 > q0w) {
#pragma unroll
                for (int u = 0; u < 2; ++u) {
                    const int thr = q0w + u * 16 + l - c - quad * 4;
#pragma unroll
                    for (int t = 0; t < 4; ++t)
#pragma unroll
                        for (int r = 0; r < 4; ++r)
                            if (t * 16 + r > thr) st[t][u][r] = -3e38f;
                }
            }
#pragma unroll
            for (int u = 0; u < 2; ++u) {
                float cmax = -3e38f;
#pragma unroll
                for (int t = 0; t < 4; ++t)
#pragma unroll
                    for (int r = 0; r < 4; ++r)
                        cmax = fmaxf(cmax, st[t][u][r]);
                cmax = fmaxf(cmax, __shfl_xor(cmax, 16));
                cmax = fmaxf(cmax, __shfl_xor(cmax, 32));
                const float mnew  = fmaxf(m_run[u], cmax);
                const float alpha = __expf(m_run[u] - mnew);
                m_run[u] = mnew;
                float csum = 0.f;
#pragma unroll
                for (int t = 0; t < 4; ++t)
#pragma unroll
                    for (int r = 0; r < 4; ++r) {
                        st[t][u][r] = __expf(st[t][u][r] - mnew);
                        csum += st[t][u][r];
                    }
                csum += __shfl_xor(csum, 16);
                csum += __shfl_xor(csum, 32);
                l_run[u] = l_run[u] * alpha + csum;
#pragma unroll
                for (int n = 0; n < 4; ++n)
#pragma unroll
                    for (int r = 0; r < 4; ++r)
                        o[n][u][r] *= alpha;
#pragma unroll
                for (int t = 0; t < 4; ++t) {
                    bf16x4 pk;
                    pk[0] = (bf16_t)st[t][u][0]; pk[1] = (bf16_t)st[t][u][1];
                    pk[2] = (bf16_t)st[t][u][2]; pk[3] = (bf16_t)st[t][u][3];
                    *(bf16x4*)(Pw + (u * 16 + l) * KLD + t * 16 + quad * 4) = pk;
                }
            }
            const bf16x8 pb00 = *(const bf16x8*)(Pw + l * KLD + quad * 8);
            const bf16x8 pb01 = *(const bf16x8*)(Pw + l * KLD + 32 + quad * 8);
            const bf16x8 pb10 = *(const bf16x8*)(Pw + (16 + l) * KLD + quad * 8);
            const bf16x8 pb11 = *(const bf16x8*)(Pw + (16 + l) * KLD + 32 + quad * 8);
#pragma unroll
            for (int n = 0; n < 4; ++n) {
                const bf16x8 v0 = *(const bf16x8*)(Vl + (n * 16 + l) * KLD + quad * 8);
                const bf16x8 v1 = *(const bf16x8*)(Vl + (n * 16 + l) * KLD + 32 + quad * 8);
                o[n][0] = MFMA16(v0, pb00, o[n][0]);
                o[n][0] = MFMA16(v1, pb01, o[n][0]);
                o[n][1] = MFMA16(v0, pb10, o[n][1]);
                o[n][1] = MFMA16(v1, pb11, o[n][1]);
            }
        }

#pragma unroll
        for (int u = 0; u < 2; ++u) {
            const float inv = 1.0f / l_run[u];
#pragma unroll
            for (int n = 0; n < 4; ++n) {
                bf16x4 ov;
                ov[0] = (bf16_t)(o[n][u][0] * inv); ov[1] = (bf16_t)(o[n][u][1] * inv);
                ov[2] = (bf16_t)(o[n][u][2] * inv); ov[3] = (bf16_t)(o[n][u][3] * inv);
                *(bf16x4*)(Pw + (u * 16 + l) * KLD + n * 16 + quad * 4) = ov;
            }
        }
        const int row  = lane >> 1;
        const int half = (lane & 1) * 32;
        const bf16x8 w0 = *(const bf16x8*)(Pw + row * KLD + half);
        const bf16x8 w1 = *(const bf16x8*)(Pw + row * KLD + half + 8);
        const bf16x8 w2 = *(const bf16x8*)(Pw + row * KLD + half + 16);
        const bf16x8 w3 = *(const bf16x8*)(Pw + row * KLD + half + 24);
        bf16_t* op = O + ((size_t)(b * SEQ + qblk * 128 + wave * 32 + row)) * DM
                       + h * DK + half;
        *(bf16x8*)(op)      = w0;
        *(bf16x8*)(op + 8)  = w1;
        *(bf16x8*)(op + 16) = w2;
        *(bf16x8*)(op + 24) = w3;
    }
}

// ---------------------------------------------------------------------------
extern "C" void kernel_launch(void* const* d_in, const int* in_sizes, int n_in,
                              void* d_out, int out_size, void* d_ws, size_t ws_size,
                              hipStream_t stream)
{
    const float* x  = (const float*)d_in[0];
    const float* Wq = (const float*)d_in[1];
    const float* Wk = (const float*)d_in[2];
    const float* Wv = (const float*)d_in[3];
    const float* Wo = (const float*)d_in[4];

    char* ws = (char*)d_ws;
    float2* rope = (float2*)ws;                        // 512 KiB
    const size_t TEN = (size_t)MROWS * DM;
    const size_t WEL = (size_t)DM * DM;
    bf16_t* xb    = (bf16_t*)(ws + (1 << 19));
    bf16_t* Wqkvt = xb + TEN;                          // [3072][1024] concat
    bf16_t* Wot   = Wqkvt + 3 * WEL;
    bf16_t* Qt    = Wot + WEL;
    bf16_t* Kt    = Qt + TEN;
    bf16_t* Vt    = Kt + TEN;
    bf16_t* Ot    = Vt + TEN;

    rope_table_kernel<<<(SEQ * 32 + 255) / 256, 256, 0, stream>>>(rope);

    cvt_kernel<<<(int)(TEN / 4 / 256), 256, 0, stream>>>(x, xb, (int)TEN);
    wtr_kernel<<<1024, 256, 0, stream>>>(Wq, Wqkvt);
    wtr_kernel<<<1024, 256, 0, stream>>>(Wk, Wqkvt + WEL);
    wtr_kernel<<<1024, 256, 0, stream>>>(Wv, Wqkvt + 2 * WEL);
    wtr_kernel<<<1024, 256, 0, stream>>>(Wo, Wot);

    // merged QKV: 64 m-tiles x 24 n-tiles, XCD-region swizzled
    gemm_qkv_kernel<<<64 * 24, 256, 0, stream>>>(xb, Wqkvt, Qt, Kt, Vt, rope);

    // grid (bh, qchunk): bid%8 = bh%8 -> per-XCD K/V locality
    attn_kernel<<<dim3(NB * NH, 8), 256, 0, stream>>>(Qt, Kt, Vt, Ot);

    gemm_out_kernel<<<64 * 8, 256, 0, stream>>>(Ot, Wot, (float*)d_out);
}

// Round 3
// 328.247 us; speedup vs baseline: 1.0399x; 1.0302x over previous
//
#include <hip/hip_runtime.h>
#include <hip/hip_bf16.h>

// Problem constants: B=4, S=2048, D=1024, H=16, dk=64
#define SEQ   2048
#define NB    4
#define NH    16
#define DK    64
#define DM    1024
#define MROWS (NB * SEQ)   // 8192

typedef __bf16 bf16_t;
typedef __bf16 bf16x8 __attribute__((ext_vector_type(8)));
typedef __bf16 bf16x4 __attribute__((ext_vector_type(4)));
typedef float  f32x4  __attribute__((ext_vector_type(4)));

#define MFMA16(a, b, c) __builtin_amdgcn_mfma_f32_16x16x32_bf16((a), (b), (c), 0, 0, 0)

// async global->LDS, 16B per lane; LDS dest wave-uniform, HW scatters +lane*16
__device__ __forceinline__ void gl2lds16(const bf16_t* g, bf16_t* l) {
    __builtin_amdgcn_global_load_lds(
        (const __attribute__((address_space(1))) unsigned int*)g,
        (__attribute__((address_space(3))) unsigned int*)l, 16, 0, 0);
}

// ---------------------------------------------------------------------------
// fp32 -> bf16 conversion (x)
// ---------------------------------------------------------------------------
__global__ __launch_bounds__(256) void cvt_kernel(
    const float* __restrict__ in, bf16_t* __restrict__ out, int n)
{
    int i = (blockIdx.x * 256 + threadIdx.x) * 4;
    if (i + 3 < n) {
        const float4 v = *(const float4*)(in + i);
        bf16x4 o;
        o[0] = (bf16_t)v.x; o[1] = (bf16_t)v.y;
        o[2] = (bf16_t)v.z; o[3] = (bf16_t)v.w;
        *(bf16x4*)(out + i) = o;
    }
}

// ---------------------------------------------------------------------------
// Weight transpose + cast: Wt[n][k] = (bf16)W[k][n].  32x32 tiles via LDS.
// ---------------------------------------------------------------------------
__global__ __launch_bounds__(256) void wtr_kernel(
    const float* __restrict__ W, bf16_t* __restrict__ Wt)
{
    __shared__ float T[32][33];
    const int tk0 = (blockIdx.x >> 5) << 5;
    const int tn0 = (blockIdx.x & 31) << 5;
    const int r = threadIdx.x >> 5, c = threadIdx.x & 31;
#pragma unroll
    for (int i = 0; i < 4; ++i)
        T[r + i * 8][c] = W[(size_t)(tk0 + r + i * 8) * DM + tn0 + c];
    __syncthreads();
#pragma unroll
    for (int i = 0; i < 4; ++i)
        Wt[(size_t)(tn0 + r + i * 8) * DM + tk0 + c] = (bf16_t)T[c][r + i * 8];
}

// ---------------------------------------------------------------------------
// RoPE table: tab[s*32+i] = (cos, sin) of s * 10000^(-i/32)
// ---------------------------------------------------------------------------
__global__ void rope_table_kernel(float2* __restrict__ tab) {
    int idx = blockIdx.x * 256 + threadIdx.x;
    if (idx >= SEQ * 32) return;
    int s = idx >> 5, i = idx & 31;
    float freq = powf(10000.0f, -(float)i / 32.0f);
    float a = (float)s * freq;
    tab[idx] = make_float2(cosf(a), sinf(a));
}

// ---------------------------------------------------------------------------
// 256x256xK(BK=64) MFMA K-loop, 8-phase schedule (T3+T4+T5).
// 512 threads = 8 waves (wm=wave&1 -> A-half, wn=wave>>1 -> 64-col B strip).
// Per-wave C = 128x64 = 8 m-frags x 4 n-frags (16x16), acc 128 VGPR.
//
// LDS = 128KB: 8 half-tile slots of 16KB.  A slots: (par*2+half)*8192 elems,
// B slots: +32768.  Each half-tile = 128 rows x 64 k, stored as 16 groups of
// 512 elems; group (rg, ks): rows rg*16..+15, k ks*32..+31, lane i holds
// (row i&15, k ks*32+(i>>4)*8) -> frag ds_read_b128 is lane-contiguous:
// ZERO bank conflicts, and gl2lds-compatible (linear dest).  Wave w stages
// row-group w of a half-tile (2 gl2lds).
//
// Per K-tile (par = t&1), 4 phases q=0..3:
//   q0: read ALL B (8 ds_read_b128, held in regs) + A rows q*32..+31 (4)
//   q1..q3: read A quarter (4)
//   each phase: [ds reads; stage (see map); barrier; 16 MFMA (setprio); barrier]
// Stage map (slot-lifetime-safe; target buffer dead before issue):
//   (0,0): A0(t+1),A1(t+1)   (0,1): B0(t+2)   (0,2): B1(t+2)   (0,3): -
//   (1,0): A0(t+2)           (1,1): A1(t+2)   (1,2): B0(t+3)   (1,3): B1(t+3)
// vmcnt(4) ONLY at phases 4 and 8 (q3): leaves the 2 newest half-tile stages
// in flight across the K-tile boundary; last iteration drains with vmcnt(0).
// TR swaps MFMA operands to produce C^T (for the V epilogue).
// ---------------------------------------------------------------------------
#define SBAR()   asm volatile("s_barrier" ::: "memory")
#define VMC(N)   asm volatile("s_waitcnt vmcnt(" #N ")" ::: "memory")

template<bool TR>
__device__ __forceinline__ void kloop256(
    const bf16_t* __restrict__ Xp, const bf16_t* __restrict__ Wp,
    bf16_t* L, int tid, f32x4 (&acc)[8][4], int kt)
{
    const int lane = tid & 63;
    const int wave = tid >> 6;        // 0..7
    const int wm   = wave & 1;        // A half this wave computes
    const int wn   = wave >> 1;       // B 64-col strip
    const int lrow = lane & 15;
    const int lcol = (lane >> 4) << 3;

    bf16_t* const As = L;
    bf16_t* const Bs = L + 4 * 8192;

    auto stA = [&](int t, int half) {
        const bf16_t* g = Xp + (size_t)(half * 128 + wave * 16 + lrow) * DM + t * 64 + lcol;
        bf16_t* s = As + ((t & 1) * 2 + half) * 8192 + wave * 1024;
        gl2lds16(g,      s);
        gl2lds16(g + 32, s + 512);
    };
    auto stB = [&](int t, int half) {
        const bf16_t* g = Wp + (size_t)(half * 128 + wave * 16 + lrow) * DM + t * 64 + lcol;
        bf16_t* s = Bs + ((t & 1) * 2 + half) * 8192 + wave * 1024;
        gl2lds16(g,      s);
        gl2lds16(g + 32, s + 512);
    };

    const bf16_t* const Aw = As + wm * 8192;          // + par*16384
    const bf16_t* const Bw = Bs + (wn >> 1) * 8192;   // + par*16384
    const int bgrp = (wn & 1) * 4;

    // prologue: K-tile 0 (A+B) + B of K-tile 1; wait all but B(1)'s 4 loads
    stA(0, 0); stA(0, 1); stB(0, 0); stB(0, 1);
    stB(1, 0); stB(1, 1);
    VMC(4);
    SBAR();

    const int nit = kt >> 1;
    for (int it = 0; it < nit; ++it) {
        const int t = 2 * it;
        const bool lst = (t + 2 >= kt);

#pragma unroll
        for (int par = 0; par < 2; ++par) {
            bf16x8 bf[8];
#pragma unroll
            for (int q = 0; q < 4; ++q) {
                // ---- ds reads ----
                const bf16_t* ap = Aw + par * 16384;
                bf16x8 a00 = *(const bf16x8*)(ap + (q * 4 + 0) * 512 + lane * 8);
                bf16x8 a01 = *(const bf16x8*)(ap + (q * 4 + 1) * 512 + lane * 8);
                bf16x8 a10 = *(const bf16x8*)(ap + (q * 4 + 2) * 512 + lane * 8);
                bf16x8 a11 = *(const bf16x8*)(ap + (q * 4 + 3) * 512 + lane * 8);
                if (q == 0) {
                    const bf16_t* bp = Bw + par * 16384;
#pragma unroll
                    for (int nf = 0; nf < 4; ++nf) {
                        bf[nf * 2]     = *(const bf16x8*)(bp + ((bgrp + nf) * 2 + 0) * 512 + lane * 8);
                        bf[nf * 2 + 1] = *(const bf16x8*)(bp + ((bgrp + nf) * 2 + 1) * 512 + lane * 8);
                    }
                }
                // ---- stage (slot-lifetime-safe map) ----
                if (par == 0) {
                    if (q == 0) { stA(t + 1, 0); stA(t + 1, 1); }
                    else if (q == 1) { if (!lst) stB(t + 2, 0); }
                    else if (q == 2) { if (!lst) stB(t + 2, 1); }
                } else {
                    if (q == 0)      { if (!lst) stA(t + 2, 0); }
                    else if (q == 1) { if (!lst) stA(t + 2, 1); }
                    else if (q == 2) { if (!lst) stB(t + 3, 0); }
                    else             { if (!lst) stB(t + 3, 1); }
                }
                SBAR();
                // ---- 16 MFMA: quadrant rows q*32..+31 x all 64 cols, K=64 ----
                __builtin_amdgcn_s_setprio(1);
#pragma unroll
                for (int nf = 0; nf < 4; ++nf) {
                    if (TR) {
                        acc[q * 2 + 0][nf] = MFMA16(bf[nf * 2],     a00, acc[q * 2 + 0][nf]);
                        acc[q * 2 + 0][nf] = MFMA16(bf[nf * 2 + 1], a01, acc[q * 2 + 0][nf]);
                        acc[q * 2 + 1][nf] = MFMA16(bf[nf * 2],     a10, acc[q * 2 + 1][nf]);
                        acc[q * 2 + 1][nf] = MFMA16(bf[nf * 2 + 1], a11, acc[q * 2 + 1][nf]);
                    } else {
                        acc[q * 2 + 0][nf] = MFMA16(a00, bf[nf * 2],     acc[q * 2 + 0][nf]);
                        acc[q * 2 + 0][nf] = MFMA16(a01, bf[nf * 2 + 1], acc[q * 2 + 0][nf]);
                        acc[q * 2 + 1][nf] = MFMA16(a10, bf[nf * 2],     acc[q * 2 + 1][nf]);
                        acc[q * 2 + 1][nf] = MFMA16(a11, bf[nf * 2 + 1], acc[q * 2 + 1][nf]);
                    }
                }
                __builtin_amdgcn_s_setprio(0);
                // ---- counted drain at K-tile boundary ----
                if (q == 3) {
                    if (par == 0) { if (lst) { VMC(0); } else { VMC(4); } }
                    else          { if (!lst) { VMC(4); } }
                }
                SBAR();
            }
        }
    }
    VMC(0);
}

// ---------------------------------------------------------------------------
// Merged QKV GEMM: C = X(8192x1024) @ Wqkv^T, Wqkv stored [3072][1024].
// 256x256 tiles: 32 mt x 12 nt = 384 blocks (8 XCD x 48, m-region swizzle).
// Epilogue by n0: n<1024 Q (RoPE*1/8), n<2048 K (RoPE), else V (C^T direct).
// ---------------------------------------------------------------------------
__global__ __launch_bounds__(512, 2) void gemm_qkv_kernel(
    const bf16_t* __restrict__ X, const bf16_t* __restrict__ Wt,
    bf16_t* __restrict__ Qt, bf16_t* __restrict__ Kt, bf16_t* __restrict__ Vtr,
    const float2* __restrict__ rope)
{
    __shared__ __align__(16) bf16_t L[8 * 8192];   // 128 KiB

    const int tid = threadIdx.x;
    const int xcd = blockIdx.x & 7;
    const int idx = blockIdx.x >> 3;               // 0..47
    const int mt  = xcd * 4 + idx / 12;            // 0..31
    const int nt  = idx % 12;                      // 0..11
    const int m0 = mt << 8, n0 = nt << 8;
    const bool tr = (n0 >= 2 * DM);

    f32x4 acc[8][4] = {};
    if (tr) kloop256<true >(X + (size_t)m0 * DM, Wt + (size_t)n0 * DM, L, tid, acc, DM / 64);
    else    kloop256<false>(X + (size_t)m0 * DM, Wt + (size_t)n0 * DM, L, tid, acc, DM / 64);

    const int lane = tid & 63;
    const int wave = tid >> 6;
    const int wm   = wave & 1, wn = wave >> 1;
    const int l    = lane & 15;
    const int quad = lane >> 4;

#pragma unroll
    for (int mf = 0; mf < 8; ++mf)
#pragma unroll
        for (int nf = 0; nf < 4; ++nf)
#pragma unroll
            for (int r = 0; r < 4; ++r) {
                float v = acc[mf][nf][r];
                if (tr) {
                    const int n = n0 + wn * 64 + nf * 16 + quad * 4 + r;
                    const int m = m0 + wm * 128 + mf * 16 + l;
                    const int bi = m >> 11, s = m & (SEQ - 1);
                    const int col = n & (DM - 1);
                    const int h = col >> 6, d = col & (DK - 1);
                    Vtr[(((size_t)(bi * NH + h)) * DK + d) * SEQ + s] = (bf16_t)v;
                } else {
                    const int m  = m0 + wm * 128 + mf * 16 + quad * 4 + r;
                    const int nn = n0 + wn * 64 + nf * 16 + l;
                    const int bi = m >> 11, s = m & (SEQ - 1);
                    const int col = nn & (DM - 1);
                    const int h = col >> 6, d = col & (DK - 1);
                    float pv = __shfl_xor(v, 1);
                    float2 cs = rope[s * 32 + (d >> 1)];
                    float res = (d & 1) ? (v * cs.x + pv * cs.y)
                                        : (v * cs.x - pv * cs.y);
                    bf16_t* dst = (nn < DM) ? Qt : Kt;
                    if (nn < DM) res *= 0.125f;   // fold 1/sqrt(dk) into Q
                    dst[(((size_t)(bi * NH + h)) * SEQ + s) * DK + d] = (bf16_t)res;
                }
            }
}

// ---------------------------------------------------------------------------
// Output projection GEMM: d_out(fp32) = Ot(8192x1024,bf16) @ Wot^T.
// 256x256 tiles: 32 mt x 4 nt = 128 blocks (8 XCD x 16 swizzle).
// ---------------------------------------------------------------------------
__global__ __launch_bounds__(512, 2) void gemm_out_kernel(
    const bf16_t* __restrict__ X, const bf16_t* __restrict__ Wt,
    float* __restrict__ out)
{
    __shared__ __align__(16) bf16_t L[8 * 8192];   // 128 KiB

    const int tid = threadIdx.x;
    const int xcd = blockIdx.x & 7;
    const int idx = blockIdx.x >> 3;               // 0..15
    const int mt  = xcd * 4 + idx / 4;             // 0..31
    const int nt  = idx & 3;                       // 0..3
    const int m0 = mt << 8, n0 = nt << 8;

    f32x4 acc[8][4] = {};
    kloop256<false>(X + (size_t)m0 * DM, Wt + (size_t)n0 * DM, L, tid, acc, DM / 64);

    const int lane = tid & 63;
    const int wave = tid >> 6;
    const int wm   = wave & 1, wn = wave >> 1;
    const int l    = lane & 15;
    const int quad = lane >> 4;

#pragma unroll
    for (int mf = 0; mf < 8; ++mf)
#pragma unroll
        for (int nf = 0; nf < 4; ++nf)
#pragma unroll
            for (int r = 0; r < 4; ++r) {
                const int m  = m0 + wm * 128 + mf * 16 + quad * 4 + r;
                const int nn = n0 + wn * 64 + nf * 16 + l;
                out[(size_t)m * DM + nn] = acc[mf][nf][r];
            }
}

// ---------------------------------------------------------------------------
// Causal flash attention.  Grid (bh, qchunk): bid%8 = bh%8 -> per-XCD K/V
// locality (8 heads x 512KB = 4MB per XCD L2).
// ---------------------------------------------------------------------------
#define KLD 72   // LDS row stride (elems): 144 B

__global__ __launch_bounds__(256) void attn_kernel(
    const bf16_t* __restrict__ Q, const bf16_t* __restrict__ K,
    const bf16_t* __restrict__ Vt, bf16_t* __restrict__ O)
{
    __shared__ __align__(16) bf16_t Kl[64 * KLD];
    __shared__ __align__(16) bf16_t Vl[64 * KLD];
    __shared__ __align__(16) bf16_t Pl[4][32 * KLD];

    const int bh   = blockIdx.x;          // swizzle: bh is fast dim
    const int qx   = blockIdx.y;          // q-chunk index 0..7
    const int tid  = threadIdx.x;
    const int wave = tid >> 6;
    const int lane = tid & 63;
    const int l    = lane & 15;
    const int quad = lane >> 4;
    const int srow = tid >> 3;
    const int sch  = (tid & 7) << 3;

    bf16_t* Pw = Pl[wave];
    const bf16_t* Qb = Q  + (size_t)bh * SEQ * DK;
    const bf16_t* Kb = K  + (size_t)bh * SEQ * DK;
    const bf16_t* Vb = Vt + (size_t)bh * DK * SEQ;
    const int b = bh >> 4, h = bh & 15;

    for (int ph = 0; ph < 2; ++ph) {
        const int qblk = ph ? (15 - qx) : qx;
        const int q0w  = qblk * 128 + wave * 32;
        const int nch  = 2 * (qblk + 1);

        bf16x8 qb[2][2];
#pragma unroll
        for (int u = 0; u < 2; ++u) {
            qb[u][0] = *(const bf16x8*)(Qb + (size_t)(q0w + u * 16 + l) * DK + quad * 8);
            qb[u][1] = *(const bf16x8*)(Qb + (size_t)(q0w + u * 16 + l) * DK + 32 + quad * 8);
        }

        float m_run[2] = {-3e38f, -3e38f};
        float l_run[2] = {0.f, 0.f};
        f32x4 o[4][2] = {};

        bf16x8 pk0 = *(const bf16x8*)(Kb + (size_t)srow * DK + sch);
        bf16x8 pk1 = *(const bf16x8*)(Kb + (size_t)(32 + srow) * DK + sch);
        bf16x8 pv0 = *(const bf16x8*)(Vb + (size_t)srow * SEQ + sch);
        bf16x8 pv1 = *(const bf16x8*)(Vb + (size_t)(32 + srow) * SEQ + sch);

        for (int i = 0; i < nch; ++i) {
            const int c = i * 64;
            __syncthreads();
            *(bf16x8*)(Kl + srow * KLD + sch)        = pk0;
            *(bf16x8*)(Kl + (32 + srow) * KLD + sch) = pk1;
            *(bf16x8*)(Vl + srow * KLD + sch)        = pv0;
            *(bf16x8*)(Vl + (32 + srow) * KLD + sch) = pv1;
            __syncthreads();
            if (i + 1 < nch) {
                const int cn = c + 64;
                pk0 = *(const bf16x8*)(Kb + (size_t)(cn + srow) * DK + sch);
                pk1 = *(const bf16x8*)(Kb + (size_t)(cn + 32 + srow) * DK + sch);
                pv0 = *(const bf16x8*)(Vb + (size_t)srow * SEQ + cn + sch);
                pv1 = *(const bf16x8*)(Vb + (size_t)(32 + srow) * SEQ + cn + sch);
            }
            if (c > q0w + 31) continue;

            f32x4 st[4][2] = {};
#pragma unroll
            for (int t = 0; t < 4; ++t) {
                const bf16x8 k0 = *(const bf16x8*)(Kl + (t * 16 + l) * KLD + quad * 8);
                const bf16x8 k1 = *(const bf16x8*)(Kl + (t * 16 + l) * KLD + 32 + quad * 8);
                st[t][0] = MFMA16(k0, qb[0][0], st[t][0]);
                st[t][0] = MFMA16(k1, qb[0][1], st[t][0]);
                st[t][1] = MFMA16(k0, qb[1][0], st[t][1]);
                st[t][1] = MFMA16(k1, qb[1][1], st[t][1]);
            }
            if (c + 63 > q0w) {
#pragma unroll
                for (int u = 0; u < 2; ++u) {
                    const int thr = q0w + u * 16 + l - c - quad * 4;
#pragma unroll
                    for (int t = 0; t < 4; ++t)
#pragma unroll
                        for (int r = 0; r < 4; ++r)
                            if (t * 16 + r > thr) st[t][u][r] = -3e38f;
                }
            }
#pragma unroll
            for (int u = 0; u < 2; ++u) {
                float cmax = -3e38f;
#pragma unroll
                for (int t = 0; t < 4; ++t)
#pragma unroll
                    for (int r = 0; r < 4; ++r)
                        cmax = fmaxf(cmax, st[t][u][r]);
                cmax = fmaxf(cmax, __shfl_xor(cmax, 16));
                cmax = fmaxf(cmax, __shfl_xor(cmax, 32));
                const float mnew  = fmaxf(m_run[u], cmax);
                const float alpha = __expf(m_run[u] - mnew);
                m_run[u] = mnew;
                float csum = 0.f;
#pragma unroll
                for (int t = 0; t < 4; ++t)
#pragma unroll
                    for (int r = 0; r < 4; ++r) {
                        st[t][u][r] = __expf(st[t][u][r] - mnew);
                        csum += st[t][u][r];
                    }
                csum += __shfl_xor(csum, 16);
                csum += __shfl_xor(csum, 32);
                l_run[u] = l_run[u] * alpha + csum;
#pragma unroll
                for (int n = 0; n < 4; ++n)
#pragma unroll
                    for (int r = 0; r < 4; ++r)
                        o[n][u][r] *= alpha;
#pragma unroll
                for (int t = 0; t < 4; ++t) {
                    bf16x4 pk;
                    pk[0] = (bf16_t)st[t][u][0]; pk[1] = (bf16_t)st[t][u][1];
                    pk[2] = (bf16_t)st[t][u][2]; pk[3] = (bf16_t)st[t][u][3];
                    *(bf16x4*)(Pw + (u * 16 + l) * KLD + t * 16 + quad * 4) = pk;
                }
            }
            const bf16x8 pb00 = *(const bf16x8*)(Pw + l * KLD + quad * 8);
            const bf16x8 pb01 = *(const bf16x8*)(Pw + l * KLD + 32 + quad * 8);
            const bf16x8 pb10 = *(const bf16x8*)(Pw + (16 + l) * KLD + quad * 8);
            const bf16x8 pb11 = *(const bf16x8*)(Pw + (16 + l) * KLD + 32 + quad * 8);
#pragma unroll
            for (int n = 0; n < 4; ++n) {
                const bf16x8 v0 = *(const bf16x8*)(Vl + (n * 16 + l) * KLD + quad * 8);
                const bf16x8 v1 = *(const bf16x8*)(Vl + (n * 16 + l) * KLD + 32 + quad * 8);
                o[n][0] = MFMA16(v0, pb00, o[n][0]);
                o[n][0] = MFMA16(v1, pb01, o[n][0]);
                o[n][1] = MFMA16(v0, pb10, o[n][1]);
                o[n][1] = MFMA16(v1, pb11, o[n][1]);
            }
        }

#pragma unroll
        for (int u = 0; u < 2; ++u) {
            const float inv = 1.0f / l_run[u];
#pragma unroll
            for (int n = 0; n < 4; ++n) {
                bf16x4 ov;
                ov[0] = (bf16_t)(o[n][u][0] * inv); ov[1] = (bf16_t)(o[n][u][1] * inv);
                ov[2] = (bf16_t)(o[n][u][2] * inv); ov[3] = (bf16_t)(o[n][u][3] * inv);
                *(bf16x4*)(Pw + (u * 16 + l) * KLD + n * 16 + quad * 4) = ov;
            }
        }
        const int row  = lane >> 1;
        const int half = (lane & 1) * 32;
        const bf16x8 w0 = *(const bf16x8*)(Pw + row * KLD + half);
        const bf16x8 w1 = *(const bf16x8*)(Pw + row * KLD + half + 8);
        const bf16x8 w2 = *(const bf16x8*)(Pw + row * KLD + half + 16);
        const bf16x8 w3 = *(const bf16x8*)(Pw + row * KLD + half + 24);
        bf16_t* op = O + ((size_t)(b * SEQ + qblk * 128 + wave * 32 + row)) * DM
                       + h * DK + half;
        *(bf16x8*)(op)      = w0;
        *(bf16x8*)(op + 8)  = w1;
        *(bf16x8*)(op + 16) = w2;
        *(bf16x8*)(op + 24) = w3;
    }
}

// ---------------------------------------------------------------------------
extern "C" void kernel_launch(void* const* d_in, const int* in_sizes, int n_in,
                              void* d_out, int out_size, void* d_ws, size_t ws_size,
                              hipStream_t stream)
{
    const float* x  = (const float*)d_in[0];
    const float* Wq = (const float*)d_in[1];
    const float* Wk = (const float*)d_in[2];
    const float* Wv = (const float*)d_in[3];
    const float* Wo = (const float*)d_in[4];

    char* ws = (char*)d_ws;
    float2* rope = (float2*)ws;                        // 512 KiB
    const size_t TEN = (size_t)MROWS * DM;
    const size_t WEL = (size_t)DM * DM;
    bf16_t* xb    = (bf16_t*)(ws + (1 << 19));
    bf16_t* Wqkvt = xb + TEN;                          // [3072][1024] concat
    bf16_t* Wot   = Wqkvt + 3 * WEL;
    bf16_t* Qt    = Wot + WEL;
    bf16_t* Kt    = Qt + TEN;
    bf16_t* Vt    = Kt + TEN;
    bf16_t* Ot    = Vt + TEN;

    rope_table_kernel<<<(SEQ * 32 + 255) / 256, 256, 0, stream>>>(rope);

    cvt_kernel<<<(int)(TEN / 4 / 256), 256, 0, stream>>>(x, xb, (int)TEN);
    wtr_kernel<<<1024, 256, 0, stream>>>(Wq, Wqkvt);
    wtr_kernel<<<1024, 256, 0, stream>>>(Wk, Wqkvt + WEL);
    wtr_kernel<<<1024, 256, 0, stream>>>(Wv, Wqkvt + 2 * WEL);
    wtr_kernel<<<1024, 256, 0, stream>>>(Wo, Wot);

    // merged QKV: 32 m-tiles x 12 n-tiles of 256^2, 8-phase schedule
    gemm_qkv_kernel<<<32 * 12, 512, 0, stream>>>(xb, Wqkvt, Qt, Kt, Vt, rope);

    // grid (bh, qchunk): bid%8 = bh%8 -> per-XCD K/V locality
    attn_kernel<<<dim3(NB * NH, 8), 256, 0, stream>>>(Qt, Kt, Vt, Ot);

    gemm_out_kernel<<<32 * 4, 512, 0, stream>>>(Ot, Wot, (float*)d_out);
}

// Round 4
// 308.529 us; speedup vs baseline: 1.1063x; 1.0639x over previous
//
#include <hip/hip_runtime.h>
#include <hip/hip_bf16.h>

// Problem constants: B=4, S=2048, D=1024, H=16, dk=64
#define SEQ   2048
#define NB    4
#define NH    16
#define DK    64
#define DM    1024
#define MROWS (NB * SEQ)   // 8192

typedef __bf16 bf16_t;
typedef __bf16 bf16x8 __attribute__((ext_vector_type(8)));
typedef __bf16 bf16x4 __attribute__((ext_vector_type(4)));
typedef float  f32x4  __attribute__((ext_vector_type(4)));

#define MFMA16(a, b, c) __builtin_amdgcn_mfma_f32_16x16x32_bf16((a), (b), (c), 0, 0, 0)

// async global->LDS, 16B per lane; LDS dest wave-uniform, HW scatters +lane*16
__device__ __forceinline__ void gl2lds16(const bf16_t* g, bf16_t* l) {
    __builtin_amdgcn_global_load_lds(
        (const __attribute__((address_space(1))) unsigned int*)g,
        (__attribute__((address_space(3))) unsigned int*)l, 16, 0, 0);
}

#define SBAR()   asm volatile("s_barrier" ::: "memory")
#define VMC(N)   asm volatile("s_waitcnt vmcnt(" #N ")" ::: "memory")

// ---------------------------------------------------------------------------
// fp32 -> bf16 conversion (x)
// ---------------------------------------------------------------------------
__global__ __launch_bounds__(256) void cvt_kernel(
    const float* __restrict__ in, bf16_t* __restrict__ out, int n)
{
    int i = (blockIdx.x * 256 + threadIdx.x) * 4;
    if (i + 3 < n) {
        const float4 v = *(const float4*)(in + i);
        bf16x4 o;
        o[0] = (bf16_t)v.x; o[1] = (bf16_t)v.y;
        o[2] = (bf16_t)v.z; o[3] = (bf16_t)v.w;
        *(bf16x4*)(out + i) = o;
    }
}

// ---------------------------------------------------------------------------
// Weight transpose + cast: Wt[n][k] = (bf16)W[k][n].  32x32 tiles via LDS.
// ---------------------------------------------------------------------------
__global__ __launch_bounds__(256) void wtr_kernel(
    const float* __restrict__ W, bf16_t* __restrict__ Wt)
{
    __shared__ float T[32][33];
    const int tk0 = (blockIdx.x >> 5) << 5;
    const int tn0 = (blockIdx.x & 31) << 5;
    const int r = threadIdx.x >> 5, c = threadIdx.x & 31;
#pragma unroll
    for (int i = 0; i < 4; ++i)
        T[r + i * 8][c] = W[(size_t)(tk0 + r + i * 8) * DM + tn0 + c];
    __syncthreads();
#pragma unroll
    for (int i = 0; i < 4; ++i)
        Wt[(size_t)(tn0 + r + i * 8) * DM + tk0 + c] = (bf16_t)T[c][r + i * 8];
}

// ---------------------------------------------------------------------------
// RoPE table: tab[s*32+i] = (cos, sin) of s * 10000^(-i/32)
// ---------------------------------------------------------------------------
__global__ void rope_table_kernel(float2* __restrict__ tab) {
    int idx = blockIdx.x * 256 + threadIdx.x;
    if (idx >= SEQ * 32) return;
    int s = idx >> 5, i = idx & 31;
    float freq = powf(10000.0f, -(float)i / 32.0f);
    float a = (float)s * freq;
    tab[idx] = make_float2(cosf(a), sinf(a));
}

// ---------------------------------------------------------------------------
// 128m x 256n x K(BK=64) MFMA K-loop, 8-phase (4 phases per K-tile pair),
// counted vmcnt (T3+T4) + setprio (T5).  512 thr = 8 waves:
//   wm = wave&1 -> A row-half (64 rows), wn = wave>>1 -> 64-col B strip.
// Per-wave C = 64x64 = 4 mf x 4 nf (16x16 frags), acc = 64 VGPR.
//
// LDS 96KB, group layout (lane-contiguous 1KB groups; gl2lds-linear, zero
// bank conflicts): group (rg,ks) holds rows rg*16..+15, k ks*32..+31; lane i
// <-> (row i&15, k ks*32+(i>>4)*8).  A: 4 slots (par,half) x 4096 elems
// (8 groups).  B: 4 slots (par,half) x 8192 elems (16 groups).
// Staging: wave w = A group w (1 gl2lds/half-tile), B groups 2w,2w+1 (2).
//
// Iter (t=2*it) phases:          reads              stages         drain
//  p0 (par0 rows 0-31 + B(t))    B 8 + A 4          A(t+1) x2      -
//  p1 (par0 rows 32-63)          A 4                B(t+2) x4      VMC(4)
//  p2 (par1 rows 0-31 + B(t+1))  B 8 + A 4          A(t+2) x2      -
//  p3 (par1 rows 32-63)          A 4                B(t+3) x4      VMC(4)
// Each phase: [ds reads; stage; SBAR; setprio1; 16 MFMA; setprio0;
//              (drain); SBAR].  FIFO per wave: each VMC(4) completes exactly
// {prev A x2, prev B x4}, keeps newest 4 in flight -- never drains mid-loop.
// Stage addresses: hoisted per-wave pointers (+=128/iter) + literal offsets.
// TR swaps MFMA operands to produce C^T (for the V epilogue).
// ---------------------------------------------------------------------------
template<bool TR>
__device__ __forceinline__ void kloop(
    const bf16_t* __restrict__ Xp, const bf16_t* __restrict__ Wp,
    bf16_t* L, int tid, f32x4 (&acc)[4][4])
{
    const int lane = tid & 63;
    const int wave = tid >> 6;        // 0..7
    const int wm   = wave & 1;        // A row-half
    const int wn   = wave >> 1;       // B 64-col strip (0..3)
    const int bh   = wn >> 1;         // B half
    const int bg   = wn & 1;          // group-block within half
    const int lrow = lane & 15;
    const int lcol = (lane >> 4) << 3;

    bf16_t* const As = L;
    bf16_t* const Bs = L + 16384;

    // staging sources (per-wave, hoisted; advance += 128 elems per iter)
    const bf16_t* pA0 = Xp + (size_t)(wn * 16 + lrow) * DM + wm * 32 + lcol;
    const bf16_t* pA1 = pA0 + (size_t)64 * DM;
    const bf16_t* pB0 = Wp + (size_t)(wave * 16 + lrow) * DM + lcol;
    const bf16_t* pB1 = pB0 + (size_t)128 * DM;

    // staging LDS dests (wave-uniform)
    bf16_t* const aldsw = As + wave * 512;
    bf16_t* const bldsw = Bs + wave * 1024;

    // fragment read bases
    const bf16_t* const Ard = As + wm * 4096;              // + par*8192 + grp*512
    const bf16_t* const Brd = Bs + bh * 8192 + bg * 4096;  // + par*16384 + nf*1024 (+512 ks1)

    // prologue: A(0), B(0), B(1); wait A(0)+B(0), keep B(1)x4 in flight
    gl2lds16(pA0,      aldsw);                 // A(0) h0  (par0: slot 0)
    gl2lds16(pA1,      aldsw + 4096);          // A(0) h1
    gl2lds16(pB0,      bldsw);                 // B(0) h0 ks0 (par0)
    gl2lds16(pB0 + 32, bldsw + 512);           //          ks1
    gl2lds16(pB1,      bldsw + 8192);          // B(0) h1
    gl2lds16(pB1 + 32, bldsw + 8704);
    gl2lds16(pB0 + 64, bldsw + 16384);         // B(1) h0 (par1)
    gl2lds16(pB0 + 96, bldsw + 16896);
    gl2lds16(pB1 + 64, bldsw + 24576);         // B(1) h1
    gl2lds16(pB1 + 96, bldsw + 25088);
    VMC(4);
    SBAR();

#define PHASE_MMA(MF0, A0, A1, A2, A3)                                       \
    __builtin_amdgcn_s_setprio(1);                                           \
    _Pragma("unroll")                                                        \
    for (int nf = 0; nf < 4; ++nf) {                                         \
        if (TR) {                                                            \
            acc[MF0][nf]     = MFMA16(bf[nf*2],   A0, acc[MF0][nf]);         \
            acc[MF0][nf]     = MFMA16(bf[nf*2+1], A1, acc[MF0][nf]);         \
            acc[MF0+1][nf]   = MFMA16(bf[nf*2],   A2, acc[MF0+1][nf]);       \
            acc[MF0+1][nf]   = MFMA16(bf[nf*2+1], A3, acc[MF0+1][nf]);       \
        } else {                                                             \
            acc[MF0][nf]     = MFMA16(A0, bf[nf*2],   acc[MF0][nf]);         \
            acc[MF0][nf]     = MFMA16(A1, bf[nf*2+1], acc[MF0][nf]);         \
            acc[MF0+1][nf]   = MFMA16(A2, bf[nf*2],   acc[MF0+1][nf]);       \
            acc[MF0+1][nf]   = MFMA16(A3, bf[nf*2+1], acc[MF0+1][nf]);       \
        }                                                                    \
    }                                                                        \
    __builtin_amdgcn_s_setprio(0);

    const int nit = (DM / 64) >> 1;   // 8
    for (int it = 0; it < nit; ++it) {
        const bool lst = (it == nit - 1);
        bf16x8 bf[8];
        bf16x8 a0, a1, a2, a3;

        // ---- p0: par0, rows 0-31; read B(t); stage A(t+1) ----
#pragma unroll
        for (int nf = 0; nf < 4; ++nf) {
            bf[nf * 2]     = *(const bf16x8*)(Brd + nf * 1024 + lane * 8);
            bf[nf * 2 + 1] = *(const bf16x8*)(Brd + nf * 1024 + 512 + lane * 8);
        }
        a0 = *(const bf16x8*)(Ard + 0 * 512 + lane * 8);
        a1 = *(const bf16x8*)(Ard + 1 * 512 + lane * 8);
        a2 = *(const bf16x8*)(Ard + 2 * 512 + lane * 8);
        a3 = *(const bf16x8*)(Ard + 3 * 512 + lane * 8);
        gl2lds16(pA0 + 64, aldsw + 8192);          // A(t+1) h0 (par1)
        gl2lds16(pA1 + 64, aldsw + 12288);         // A(t+1) h1
        SBAR();
        PHASE_MMA(0, a0, a1, a2, a3)
        SBAR();

        // ---- p1: par0, rows 32-63; stage B(t+2); drain ----
        a0 = *(const bf16x8*)(Ard + 4 * 512 + lane * 8);
        a1 = *(const bf16x8*)(Ard + 5 * 512 + lane * 8);
        a2 = *(const bf16x8*)(Ard + 6 * 512 + lane * 8);
        a3 = *(const bf16x8*)(Ard + 7 * 512 + lane * 8);
        if (!lst) {
            gl2lds16(pB0 + 128, bldsw);            // B(t+2) h0 (par0)
            gl2lds16(pB0 + 160, bldsw + 512);
            gl2lds16(pB1 + 128, bldsw + 8192);     // B(t+2) h1
            gl2lds16(pB1 + 160, bldsw + 8704);
        }
        SBAR();
        PHASE_MMA(2, a0, a1, a2, a3)
        if (lst) { VMC(0); } else { VMC(4); }      // completes A(t+1)+B(t+1)
        SBAR();

        // ---- p2: par1, rows 0-31; read B(t+1); stage A(t+2) ----
#pragma unroll
        for (int nf = 0; nf < 4; ++nf) {
            bf[nf * 2]     = *(const bf16x8*)(Brd + 16384 + nf * 1024 + lane * 8);
            bf[nf * 2 + 1] = *(const bf16x8*)(Brd + 16384 + nf * 1024 + 512 + lane * 8);
        }
        a0 = *(const bf16x8*)(Ard + 8192 + 0 * 512 + lane * 8);
        a1 = *(const bf16x8*)(Ard + 8192 + 1 * 512 + lane * 8);
        a2 = *(const bf16x8*)(Ard + 8192 + 2 * 512 + lane * 8);
        a3 = *(const bf16x8*)(Ard + 8192 + 3 * 512 + lane * 8);
        if (!lst) {
            gl2lds16(pA0 + 128, aldsw);            // A(t+2) h0 (par0)
            gl2lds16(pA1 + 128, aldsw + 4096);     // A(t+2) h1
        }
        SBAR();
        PHASE_MMA(0, a0, a1, a2, a3)
        SBAR();

        // ---- p3: par1, rows 32-63; stage B(t+3); drain ----
        a0 = *(const bf16x8*)(Ard + 8192 + 4 * 512 + lane * 8);
        a1 = *(const bf16x8*)(Ard + 8192 + 5 * 512 + lane * 8);
        a2 = *(const bf16x8*)(Ard + 8192 + 6 * 512 + lane * 8);
        a3 = *(const bf16x8*)(Ard + 8192 + 7 * 512 + lane * 8);
        if (!lst) {
            gl2lds16(pB0 + 192, bldsw + 16384);    // B(t+3) h0 (par1)
            gl2lds16(pB0 + 224, bldsw + 16896);
            gl2lds16(pB1 + 192, bldsw + 24576);    // B(t+3) h1
            gl2lds16(pB1 + 224, bldsw + 25088);
        }
        SBAR();
        PHASE_MMA(2, a0, a1, a2, a3)
        if (lst) { VMC(0); } else { VMC(4); }      // completes A(t+2)+B(t+2)
        SBAR();

        pA0 += 128; pA1 += 128; pB0 += 128; pB1 += 128;
    }
#undef PHASE_MMA
}

// ---------------------------------------------------------------------------
// Merged QKV GEMM: C = X(8192x1024) @ Wqkv^T, Wqkv stored [3072][1024].
// 128x256 tiles: 64 mt x 12 nt = 768 blocks = EXACTLY 3 dispatch rounds.
// XCD swizzle: xcd owns 8mt x 12nt; within region m-fastest so 32 co-resident
// blocks touch 8 A-panels (2MB) + 4 B-panels (2MB) = 4MB L2.
// Epilogue by col: <1024 Q (RoPE*1/8), <2048 K (RoPE), else V (C^T direct).
// ---------------------------------------------------------------------------
__global__ __launch_bounds__(512, 2) void gemm_qkv_kernel(
    const bf16_t* __restrict__ X, const bf16_t* __restrict__ Wt,
    bf16_t* __restrict__ Qt, bf16_t* __restrict__ Kt, bf16_t* __restrict__ Vtr,
    const float2* __restrict__ rope)
{
    __shared__ __align__(16) bf16_t L[49152];   // 96 KiB

    const int tid = threadIdx.x;
    const int xcd = blockIdx.x & 7;
    const int idx = blockIdx.x >> 3;               // 0..95
    const int mt  = xcd * 8 + (idx & 7);           // 0..63
    const int nt  = idx >> 3;                      // 0..11
    const int m0 = mt << 7, n0 = nt << 8;
    const bool tr = (n0 >= 2 * DM);

    f32x4 acc[4][4] = {};
    if (tr) kloop<true >(X + (size_t)m0 * DM, Wt + (size_t)n0 * DM, L, tid, acc);
    else    kloop<false>(X + (size_t)m0 * DM, Wt + (size_t)n0 * DM, L, tid, acc);

    const int lane = tid & 63;
    const int wave = tid >> 6;
    const int wm   = wave & 1, wn = wave >> 1;
    const int l    = lane & 15;
    const int quad = lane >> 4;

#pragma unroll
    for (int mf = 0; mf < 4; ++mf)
#pragma unroll
        for (int nf = 0; nf < 4; ++nf)
#pragma unroll
            for (int r = 0; r < 4; ++r) {
                float v = acc[mf][nf][r];
                if (tr) {
                    const int n = n0 + wn * 64 + nf * 16 + quad * 4 + r;
                    const int m = m0 + wm * 64 + mf * 16 + l;
                    const int bi = m >> 11, s = m & (SEQ - 1);
                    const int col = n & (DM - 1);
                    const int h = col >> 6, d = col & (DK - 1);
                    Vtr[(((size_t)(bi * NH + h)) * DK + d) * SEQ + s] = (bf16_t)v;
                } else {
                    const int m  = m0 + wm * 64 + mf * 16 + quad * 4 + r;
                    const int nn = n0 + wn * 64 + nf * 16 + l;
                    const int bi = m >> 11, s = m & (SEQ - 1);
                    const int col = nn & (DM - 1);
                    const int h = col >> 6, d = col & (DK - 1);
                    float pv = __shfl_xor(v, 1);
                    float2 cs = rope[s * 32 + (d >> 1)];
                    float res = (d & 1) ? (v * cs.x + pv * cs.y)
                                        : (v * cs.x - pv * cs.y);
                    bf16_t* dst = (nn < DM) ? Qt : Kt;
                    if (nn < DM) res *= 0.125f;   // fold 1/sqrt(dk) into Q
                    dst[(((size_t)(bi * NH + h)) * SEQ + s) * DK + d] = (bf16_t)res;
                }
            }
}

// ---------------------------------------------------------------------------
// Output projection GEMM: d_out(fp32) = Ot(8192x1024,bf16) @ Wot^T.
// 128x256 tiles: 64 mt x 4 nt = 256 blocks = EXACTLY 1 full round
// (vs previous 128-block config that left half the GPU idle).
// ---------------------------------------------------------------------------
__global__ __launch_bounds__(512, 2) void gemm_out_kernel(
    const bf16_t* __restrict__ X, const bf16_t* __restrict__ Wt,
    float* __restrict__ out)
{
    __shared__ __align__(16) bf16_t L[49152];   // 96 KiB

    const int tid = threadIdx.x;
    const int xcd = blockIdx.x & 7;
    const int idx = blockIdx.x >> 3;               // 0..31
    const int mt  = xcd * 8 + (idx & 7);           // 0..63
    const int nt  = idx >> 3;                      // 0..3
    const int m0 = mt << 7, n0 = nt << 8;

    f32x4 acc[4][4] = {};
    kloop<false>(X + (size_t)m0 * DM, Wt + (size_t)n0 * DM, L, tid, acc);

    const int lane = tid & 63;
    const int wave = tid >> 6;
    const int wm   = wave & 1, wn = wave >> 1;
    const int l    = lane & 15;
    const int quad = lane >> 4;

#pragma unroll
    for (int mf = 0; mf < 4; ++mf)
#pragma unroll
        for (int nf = 0; nf < 4; ++nf)
#pragma unroll
            for (int r = 0; r < 4; ++r) {
                const int m  = m0 + wm * 64 + mf * 16 + quad * 4 + r;
                const int nn = n0 + wn * 64 + nf * 16 + l;
                out[(size_t)m * DM + nn] = acc[mf][nf][r];
            }
}

// ---------------------------------------------------------------------------
// Causal flash attention.  Grid (bh, qchunk): bid%8 = bh%8 -> per-XCD K/V
// locality (8 heads x 512KB = 4MB per XCD L2).
// ---------------------------------------------------------------------------
#define KLD 72   // LDS row stride (elems): 144 B

__global__ __launch_bounds__(256) void attn_kernel(
    const bf16_t* __restrict__ Q, const bf16_t* __restrict__ K,
    const bf16_t* __restrict__ Vt, bf16_t* __restrict__ O)
{
    __shared__ __align__(16) bf16_t Kl[64 * KLD];
    __shared__ __align__(16) bf16_t Vl[64 * KLD];
    __shared__ __align__(16) bf16_t Pl[4][32 * KLD];

    const int bh   = blockIdx.x;          // swizzle: bh is fast dim
    const int qx   = blockIdx.y;          // q-chunk index 0..7
    const int tid  = threadIdx.x;
    const int wave = tid >> 6;
    const int lane = tid & 63;
    const int l    = lane & 15;
    const int quad = lane >> 4;
    const int srow = tid >> 3;
    const int sch  = (tid & 7) << 3;

    bf16_t* Pw = Pl[wave];
    const bf16_t* Qb = Q  + (size_t)bh * SEQ * DK;
    const bf16_t* Kb = K  + (size_t)bh * SEQ * DK;
    const bf16_t* Vb = Vt + (size_t)bh * DK * SEQ;
    const int b = bh >> 4, h = bh & 15;

    for (int ph = 0; ph < 2; ++ph) {
        const int qblk = ph ? (15 - qx) : qx;
        const int q0w  = qblk * 128 + wave * 32;
        const int nch  = 2 * (qblk + 1);

        bf16x8 qb[2][2];
#pragma unroll
        for (int u = 0; u < 2; ++u) {
            qb[u][0] = *(const bf16x8*)(Qb + (size_t)(q0w + u * 16 + l) * DK + quad * 8);
            qb[u][1] = *(const bf16x8*)(Qb + (size_t)(q0w + u * 16 + l) * DK + 32 + quad * 8);
        }

        float m_run[2] = {-3e38f, -3e38f};
        float l_run[2] = {0.f, 0.f};
        f32x4 o[4][2] = {};

        bf16x8 pk0 = *(const bf16x8*)(Kb + (size_t)srow * DK + sch);
        bf16x8 pk1 = *(const bf16x8*)(Kb + (size_t)(32 + srow) * DK + sch);
        bf16x8 pv0 = *(const bf16x8*)(Vb + (size_t)srow * SEQ + sch);
        bf16x8 pv1 = *(const bf16x8*)(Vb + (size_t)(32 + srow) * SEQ + sch);

        for (int i = 0; i < nch; ++i) {
            const int c = i * 64;
            __syncthreads();
            *(bf16x8*)(Kl + srow * KLD + sch)        = pk0;
            *(bf16x8*)(Kl + (32 + srow) * KLD + sch) = pk1;
            *(bf16x8*)(Vl + srow * KLD + sch)        = pv0;
            *(bf16x8*)(Vl + (32 + srow) * KLD + sch) = pv1;
            __syncthreads();
            if (i + 1 < nch) {
                const int cn = c + 64;
                pk0 = *(const bf16x8*)(Kb + (size_t)(cn + srow) * DK + sch);
                pk1 = *(const bf16x8*)(Kb + (size_t)(cn + 32 + srow) * DK + sch);
                pv0 = *(const bf16x8*)(Vb + (size_t)srow * SEQ + cn + sch);
                pv1 = *(const bf16x8*)(Vb + (size_t)(32 + srow) * SEQ + cn + sch);
            }
            if (c > q0w + 31) continue;

            f32x4 st[4][2] = {};
#pragma unroll
            for (int t = 0; t < 4; ++t) {
                const bf16x8 k0 = *(const bf16x8*)(Kl + (t * 16 + l) * KLD + quad * 8);
                const bf16x8 k1 = *(const bf16x8*)(Kl + (t * 16 + l) * KLD + 32 + quad * 8);
                st[t][0] = MFMA16(k0, qb[0][0], st[t][0]);
                st[t][0] = MFMA16(k1, qb[0][1], st[t][0]);
                st[t][1] = MFMA16(k0, qb[1][0], st[t][1]);
                st[t][1] = MFMA16(k1, qb[1][1], st[t][1]);
            }
            if (c + 63 > q0w) {
#pragma unroll
                for (int u = 0; u < 2; ++u) {
                    const int thr = q0w + u * 16 + l - c - quad * 4;
#pragma unroll
                    for (int t = 0; t < 4; ++t)
#pragma unroll
                        for (int r = 0; r < 4; ++r)
                            if (t * 16 + r > thr) st[t][u][r] = -3e38f;
                }
            }
#pragma unroll
            for (int u = 0; u < 2; ++u) {
                float cmax = -3e38f;
#pragma unroll
                for (int t = 0; t < 4; ++t)
#pragma unroll
                    for (int r = 0; r < 4; ++r)
                        cmax = fmaxf(cmax, st[t][u][r]);
                cmax = fmaxf(cmax, __shfl_xor(cmax, 16));
                cmax = fmaxf(cmax, __shfl_xor(cmax, 32));
                const float mnew  = fmaxf(m_run[u], cmax);
                const float alpha = __expf(m_run[u] - mnew);
                m_run[u] = mnew;
                float csum = 0.f;
#pragma unroll
                for (int t = 0; t < 4; ++t)
#pragma unroll
                    for (int r = 0; r < 4; ++r) {
                        st[t][u][r] = __expf(st[t][u][r] - mnew);
                        csum += st[t][u][r];
                    }
                csum += __shfl_xor(csum, 16);
                csum += __shfl_xor(csum, 32);
                l_run[u] = l_run[u] * alpha + csum;
#pragma unroll
                for (int n = 0; n < 4; ++n)
#pragma unroll
                    for (int r = 0; r < 4; ++r)
                        o[n][u][r] *= alpha;
#pragma unroll
                for (int t = 0; t < 4; ++t) {
                    bf16x4 pk;
                    pk[0] = (bf16_t)st[t][u][0]; pk[1] = (bf16_t)st[t][u][1];
                    pk[2] = (bf16_t)st[t][u][2]; pk[3] = (bf16_t)st[t][u][3];
                    *(bf16x4*)(Pw + (u * 16 + l) * KLD + t * 16 + quad * 4) = pk;
                }
            }
            const bf16x8 pb00 = *(const bf16x8*)(Pw + l * KLD + quad * 8);
            const bf16x8 pb01 = *(const bf16x8*)(Pw + l * KLD + 32 + quad * 8);
            const bf16x8 pb10 = *(const bf16x8*)(Pw + (16 + l) * KLD + quad * 8);
            const bf16x8 pb11 = *(const bf16x8*)(Pw + (16 + l) * KLD + 32 + quad * 8);
#pragma unroll
            for (int n = 0; n < 4; ++n) {
                const bf16x8 v0 = *(const bf16x8*)(Vl + (n * 16 + l) * KLD + quad * 8);
                const bf16x8 v1 = *(const bf16x8*)(Vl + (n * 16 + l) * KLD + 32 + quad * 8);
                o[n][0] = MFMA16(v0, pb00, o[n][0]);
                o[n][0] = MFMA16(v1, pb01, o[n][0]);
                o[n][1] = MFMA16(v0, pb10, o[n][1]);
                o[n][1] = MFMA16(v1, pb11, o[n][1]);
            }
        }

#pragma unroll
        for (int u = 0; u < 2; ++u) {
            const float inv = 1.0f / l_run[u];
#pragma unroll
            for (int n = 0; n < 4; ++n) {
                bf16x4 ov;
                ov[0] = (bf16_t)(o[n][u][0] * inv); ov[1] = (bf16_t)(o[n][u][1] * inv);
                ov[2] = (bf16_t)(o[n][u][2] * inv); ov[3] = (bf16_t)(o[n][u][3] * inv);
                *(bf16x4*)(Pw + (u * 16 + l) * KLD + n * 16 + quad * 4) = ov;
            }
        }
        const int row  = lane >> 1;
        const int half = (lane & 1) * 32;
        const bf16x8 w0 = *(const bf16x8*)(Pw + row * KLD + half);
        const bf16x8 w1 = *(const bf16x8*)(Pw + row * KLD + half + 8);
        const bf16x8 w2 = *(const bf16x8*)(Pw + row * KLD + half + 16);
        const bf16x8 w3 = *(const bf16x8*)(Pw + row * KLD + half + 24);
        bf16_t* op = O + ((size_t)(b * SEQ + qblk * 128 + wave * 32 + row)) * DM
                       + h * DK + half;
        *(bf16x8*)(op)      = w0;
        *(bf16x8*)(op + 8)  = w1;
        *(bf16x8*)(op + 16) = w2;
        *(bf16x8*)(op + 24) = w3;
    }
}

// ---------------------------------------------------------------------------
extern "C" void kernel_launch(void* const* d_in, const int* in_sizes, int n_in,
                              void* d_out, int out_size, void* d_ws, size_t ws_size,
                              hipStream_t stream)
{
    const float* x  = (const float*)d_in[0];
    const float* Wq = (const float*)d_in[1];
    const float* Wk = (const float*)d_in[2];
    const float* Wv = (const float*)d_in[3];
    const float* Wo = (const float*)d_in[4];

    char* ws = (char*)d_ws;
    float2* rope = (float2*)ws;                        // 512 KiB
    const size_t TEN = (size_t)MROWS * DM;
    const size_t WEL = (size_t)DM * DM;
    bf16_t* xb    = (bf16_t*)(ws + (1 << 19));
    bf16_t* Wqkvt = xb + TEN;                          // [3072][1024] concat
    bf16_t* Wot   = Wqkvt + 3 * WEL;
    bf16_t* Qt    = Wot + WEL;
    bf16_t* Kt    = Qt + TEN;
    bf16_t* Vt    = Kt + TEN;
    bf16_t* Ot    = Vt + TEN;

    rope_table_kernel<<<(SEQ * 32 + 255) / 256, 256, 0, stream>>>(rope);

    cvt_kernel<<<(int)(TEN / 4 / 256), 256, 0, stream>>>(x, xb, (int)TEN);
    wtr_kernel<<<1024, 256, 0, stream>>>(Wq, Wqkvt);
    wtr_kernel<<<1024, 256, 0, stream>>>(Wk, Wqkvt + WEL);
    wtr_kernel<<<1024, 256, 0, stream>>>(Wv, Wqkvt + 2 * WEL);
    wtr_kernel<<<1024, 256, 0, stream>>>(Wo, Wot);

    // merged QKV: 64 mt x 12 nt of 128x256, 8-phase schedule, 3 exact rounds
    gemm_qkv_kernel<<<64 * 12, 512, 0, stream>>>(xb, Wqkvt, Qt, Kt, Vt, rope);

    // grid (bh, qchunk): bid%8 = bh%8 -> per-XCD K/V locality
    attn_kernel<<<dim3(NB * NH, 8), 256, 0, stream>>>(Qt, Kt, Vt, Ot);

    // out: 64 mt x 4 nt of 128x256 = 256 blocks = 1 exact round
    gemm_out_kernel<<<64 * 4, 512, 0, stream>>>(Ot, Wot, (float*)d_out);
}